// Round 2
// baseline (275.727 us; speedup 1.0000x reference)
//
#include <hip/hip_runtime.h>

typedef float  f32x4  __attribute__((ext_vector_type(4)));
typedef __bf16 bf16x8 __attribute__((ext_vector_type(8)));
typedef __bf16 bf16x4 __attribute__((ext_vector_type(4)));

#define D_MODEL 512
#define SEQ     2048
#define BATCH   8
#define ROWS    (BATCH * SEQ)   // 16384

// async 16B global -> LDS (each lane deposits at lds_base + lane*16B)
#define ASYNC_COPY16(dst_lds, src_glb)                                          \
  __builtin_amdgcn_global_load_lds(                                             \
      (const __attribute__((address_space(1))) void*)(src_glb),                 \
      (__attribute__((address_space(3))) void*)(dst_lds), 16, 0, 0)

// ------------------------------------------------------------ fused converts
__global__ void cvt_all_kernel(const float* __restrict__ x1,
                               const float* __restrict__ x2,
                               const float* __restrict__ posb,
                               const float* __restrict__ Wq,
                               const float* __restrict__ Wk,
                               const float* __restrict__ Wv,
                               __bf16* __restrict__ x1b, __bf16* __restrict__ x2b,
                               __bf16* __restrict__ expBb, __bf16* __restrict__ wb)
{
  const int blk = blockIdx.x;
  if (blk < 16384) {
    const float* in = (blk < 8192) ? x1 : x2;
    __bf16* out = (blk < 8192) ? x1b : x2b;
    const int i = (blk & 8191) * 256 + threadIdx.x;
    float4 v = ((const float4*)in)[i];
    bf16x4 o = { (__bf16)v.x, (__bf16)v.y, (__bf16)v.z, (__bf16)v.w };
    ((bf16x4*)out)[i] = o;
  } else if (blk < 20480) {
    const int i = (blk - 16384) * 256 + threadIdx.x;
    float4 v = ((const float4*)posb)[i];
    bf16x4 o = { (__bf16)__expf(v.x), (__bf16)__expf(v.y),
                 (__bf16)__expf(v.z), (__bf16)__expf(v.w) };
    ((bf16x4*)expBb)[i] = o;
  } else {
    const int i = (blk - 20480) * 256 + threadIdx.x;
    const int nW4 = D_MODEL * D_MODEL / 4;
    const float* src = (i < nW4) ? Wq : (i < 2 * nW4) ? Wk : Wv;
    const int ii = i - ((i < nW4) ? 0 : (i < 2 * nW4) ? nW4 : 2 * nW4);
    float4 v = ((const float4*)src)[ii];
    bf16x4 o = { (__bf16)v.x, (__bf16)v.y, (__bf16)v.z, (__bf16)v.w };
    ((bf16x4*)wb)[i] = o;
  }
}

// ------------------------------------------------------------- tri-GEMM
// One launch, 3 GEMMs (z). 128x128 tile / BK=64, double-buffered LDS,
// flat 16-step loop (2 row-tiles x 8 K-steps). Per kk-phase:
// {8 ds_read -> stage 4 copies for step s+1 -> barrier -> lgkmcnt(0) ->
//  setprio(1) -> 16 MFMA -> setprio(0) -> barrier}. Top-of-step vmcnt(0)
// waits only on >=1-phase-old loads (no young loads in queue by design).
// z=0: q    = x1*Wq^T  -> sigmoid -> sigq [rows][d]
// z=1: kT   = Wk*x1^T  -> + bk    -> kT  [d][rows]
// z=2: vT   = Wv*x2^T  -> + bv    -> vT  [d][rows]
__global__ __launch_bounds__(256) void tri_gemm_kernel(
    const __bf16* __restrict__ x1b, const __bf16* __restrict__ x2b,
    const __bf16* __restrict__ wb,
    const float* __restrict__ bq, const float* __restrict__ bk,
    const float* __restrict__ bv,
    __bf16* __restrict__ sigq, __bf16* __restrict__ kT,
    __bf16* __restrict__ vT)
{
  __shared__ __align__(16) __bf16 As[2][128 * 64];
  __shared__ __align__(16) __bf16 Bs[2][128 * 64];

  const int K = D_MODEL;
  const int z = blockIdx.z;
  const int tid  = threadIdx.x;
  const int wave = tid >> 6;
  const int lane = tid & 63;
  const int quad = lane >> 4;
  const int l16  = lane & 15;
  const int wm   = (wave >> 1) * 64;
  const int wn   = (wave & 1) * 64;
  const int l8r = lane >> 3;
  const int scol = ((lane & 7) ^ l8r) * 8;
  const int F0 = blockIdx.y * 128;              // fixed-dim tile (d side)

  const __bf16* Ap = (z == 0) ? x1b
                   : (z == 1) ? (wb + (long long)D_MODEL * D_MODEL)
                              : (wb + 2LL * D_MODEL * D_MODEL);
  const __bf16* Bp = (z == 0) ? wb : (z == 1) ? x1b : x2b;

  const int srow = wave * 8 + l8r;              // staging row within 32-group

  const __bf16* ga[4]; const __bf16* gb[4];
  auto set_tile = [&](int t) {
    const int L0 = (blockIdx.x * 2 + t) * 128;
    const int m0 = (z == 0) ? L0 : F0;
    const int n0 = (z == 0) ? F0 : L0;
    #pragma unroll
    for (int i = 0; i < 4; ++i) {
      ga[i] = Ap + (long long)(m0 + i * 32 + srow) * K + scol;
      gb[i] = Bp + (long long)(n0 + i * 32 + srow) * K + scol;
    }
  };
  auto stageA = [&](int c, int k0) {
    #pragma unroll
    for (int i = 0; i < 4; ++i)
      ASYNC_COPY16(&As[c][(i * 32 + wave * 8) * 64], ga[i] + k0);
  };
  auto stageB = [&](int c, int k0) {
    #pragma unroll
    for (int i = 0; i < 4; ++i)
      ASYNC_COPY16(&Bs[c][(i * 32 + wave * 8) * 64], gb[i] + k0);
  };

  set_tile(0);
  stageA(0, 0);
  stageB(0, 0);                                 // prologue

  f32x4 acc[4][4];
  #pragma unroll
  for (int i = 0; i < 4; ++i)
    #pragma unroll
    for (int j = 0; j < 4; ++j) acc[i][j] = (f32x4){0.f, 0.f, 0.f, 0.f};

  for (int s = 0; s < 16; ++s) {
    const int c = s & 1;
    asm volatile("s_waitcnt vmcnt(0)" ::: "memory");  // old loads only: cheap
    __builtin_amdgcn_s_barrier();                     // deposits visible
    __builtin_amdgcn_sched_barrier(0);

    const bool pf = (s + 1 < 16);
    const int k1 = ((s + 1) & 7) * 64;

    #pragma unroll
    for (int kk = 0; kk < 2; ++kk) {
      const int slot = ((quad + kk * 4) ^ (l16 & 7)) * 8;
      bf16x8 af[4], bfr[4];
      #pragma unroll
      for (int i = 0; i < 4; ++i)
        af[i] = *(const bf16x8*)&As[c][(wm + i * 16 + l16) * 64 + slot];
      #pragma unroll
      for (int j = 0; j < 4; ++j)
        bfr[j] = *(const bf16x8*)&Bs[c][(wn + j * 16 + l16) * 64 + slot];
      if (pf) {
        if (kk == 0) {
          if (s == 7) set_tile(1);
          stageA(c ^ 1, k1);                    // issue hides under MFMA
        } else {
          stageB(c ^ 1, k1);
        }
      }
      __builtin_amdgcn_s_barrier();
      asm volatile("s_waitcnt lgkmcnt(0)" ::: "memory");
      __builtin_amdgcn_sched_barrier(0);        // rule #18: pin MFMA after wait
      __builtin_amdgcn_s_setprio(1);
      #pragma unroll
      for (int i = 0; i < 4; ++i)
        #pragma unroll
        for (int j = 0; j < 4; ++j)
          acc[i][j] = __builtin_amdgcn_mfma_f32_16x16x32_bf16(af[i], bfr[j],
                                                              acc[i][j], 0, 0, 0);
      __builtin_amdgcn_s_setprio(0);
      __builtin_amdgcn_s_barrier();
    }

    if ((s & 7) == 7) {
      // epilogue for tile t = s>>3: C/D layout col = lane&15, row = quad*4+reg
      const int t = s >> 3;
      const int L0 = (blockIdx.x * 2 + t) * 128;
      if (z == 0) {
        const int m0 = L0, n0 = F0;
        #pragma unroll
        for (int j = 0; j < 4; ++j) {
          const int col = n0 + wn + j * 16 + l16;       // d
          const float bvv = bq[col];
          #pragma unroll
          for (int i = 0; i < 4; ++i)
            #pragma unroll
            for (int r = 0; r < 4; ++r) {
              const int row = m0 + wm + i * 16 + quad * 4 + r;
              float x = acc[i][j][r] + bvv;
              sigq[(long long)row * D_MODEL + col] =
                  (__bf16)(1.f / (1.f + __expf(-x)));
            }
        }
      } else {
        const int m0 = F0, n0 = L0;
        const float* bias = (z == 1) ? bk : bv;
        __bf16* outp = (z == 1) ? kT : vT;
        #pragma unroll
        for (int i = 0; i < 4; ++i) {
          #pragma unroll
          for (int r = 0; r < 4; ++r) {
            const int d = m0 + wm + i * 16 + quad * 4 + r;
            const float bvv = bias[d];
            #pragma unroll
            for (int j = 0; j < 4; ++j) {
              const int rr = n0 + wn + j * 16 + l16;    // global row 0..16383
              outp[(long long)d * ROWS + rr] = (__bf16)(acc[i][j][r] + bvv);
            }
          }
        }
      }
      if (s == 7) {
        #pragma unroll
        for (int i = 0; i < 4; ++i)
          #pragma unroll
          for (int j = 0; j < 4; ++j) acc[i][j] = (f32x4){0.f, 0.f, 0.f, 0.f};
      }
    }
  }
}

// ------------------------------------------------------ streaming combine
__global__ __launch_bounds__(256) void combine_kernel(
    const __bf16* __restrict__ kT, const __bf16* __restrict__ vT,
    __bf16* __restrict__ ekvT)
{
  const int c = blockIdx.x * 256 + threadIdx.x;   // 16B chunk id, 0..2^20-1
  const int d   = c >> 11;                        // 2048 chunks per d-row
  const int off = (c & 2047) * 8;                 // position in 16384 rows
  const int b = off >> 11;
  const int s = off & 2047;

  bf16x8 kk = *(const bf16x8*)(kT + (long long)d * ROWS + off);
  bf16x8 vv = *(const bf16x8*)(vT + (long long)d * ROWS + off);
  bf16x8 ek, ev;
  #pragma unroll
  for (int e = 0; e < 8; ++e) {
    float ekf = __expf((float)kk[e]);
    ek[e] = (__bf16)ekf;
    ev[e] = (__bf16)(ekf * (float)vv[e]);
  }
  const int gr = ((d >> 5) << 6) + (d & 31);
  __bf16* outp = ekvT + (long long)b * (2 * D_MODEL) * SEQ + s;
  *(bf16x8*)(outp + (long long)gr * SEQ)        = ev;
  *(bf16x8*)(outp + (long long)(gr + 32) * SEQ) = ek;
}

// -------------------------------------------- einsum + final, fused epilogue
// 256x256 tile, BK=64, 8 waves (2Mx4N), double-buffered 128 KiB LDS.
// Staging for tile t+1 is SPREAD across tile t's phases (pairs {0,1} in
// phase 0, pairs {2,3} in phase 1), issued after that phase's ds_reads so
// VMEM issue hides under MFMA (m196 lesson). At tile top the youngest
// outstanding load is >=3 phases (~1900 cyc) old > HBM latency, so the
// vmcnt(0) there is a straggler-check, not a drain of young loads.
#define EBM 256
#define EBN 256
#define EBK 64
#define ENT (SEQ / EBK)   // 32

__global__ __launch_bounds__(512) void einsum_fused_kernel(
    const __bf16* __restrict__ A, const __bf16* __restrict__ BtAll,
    const __bf16* __restrict__ sigq, float* __restrict__ out)
{
  extern __shared__ __align__(16) __bf16 smem[];  // A[2][16384] | B[2][16384]

  const int b = blockIdx.z;
  const __bf16* Bt = BtAll + (long long)b * (2 * D_MODEL) * SEQ;

  const int tid  = threadIdx.x;
  const int wave = tid >> 6;
  const int lane = tid & 63;
  const int quad = lane >> 4;
  const int l16  = lane & 15;
  const int wm   = (wave >> 2) * 128;             // 2 wave-rows of 128
  const int wn   = (wave & 3) * 64;               // 4 wave-cols of 64
  const int m0   = blockIdx.x * EBM;
  const int n0   = blockIdx.y * EBN;
  const int l8r  = lane >> 3;
  const int scol = ((lane & 7) ^ l8r) * 8;        // pre-swizzled global col

  const __bf16* gA = A  + (long long)(m0 + wave * 8 + l8r) * SEQ + scol;
  const __bf16* gB = Bt + (long long)(n0 + wave * 8 + l8r) * SEQ + scol;
  __bf16* lA = smem +         (wave * 8) * 64;
  __bf16* lB = smem + 32768 + (wave * 8) * 64;

  f32x4 acc[8][4];
  #pragma unroll
  for (int i = 0; i < 8; ++i)
    #pragma unroll
    for (int j = 0; j < 4; ++j) acc[i][j] = (f32x4){0.f, 0.f, 0.f, 0.f};

  // pair i covers A rows [i*64,+64) and B rows [i*64,+64) of the 256-row tile
  auto stage_pair = [&](int c, int k0, int i) {
    ASYNC_COPY16(lA + c * 16384 + i * 4096, gA + (long long)i * 64 * SEQ + k0);
    ASYNC_COPY16(lB + c * 16384 + i * 4096, gB + (long long)i * 64 * SEQ + k0);
  };

  #pragma unroll
  for (int i = 0; i < 4; ++i) stage_pair(0, 0, i);   // prologue burst (once)

  const int s0 = ((quad    ) ^ (l16 & 7)) * 8;    // k-slice 0 slot
  const int s1 = ((quad + 4) ^ (l16 & 7)) * 8;    // k-slice 1 slot

  for (int t = 0; t < ENT; ++t) {
    const int c = t & 1;
    asm volatile("s_waitcnt vmcnt(0)" ::: "memory");  // old loads only
    __builtin_amdgcn_s_barrier();                     // deposits visible
    __builtin_amdgcn_sched_barrier(0);

    const __bf16* Ac = smem +         c * 16384 + (wm + l16) * 64;
    const __bf16* Bc = smem + 32768 + c * 16384 + (wn + l16) * 64;
    const bool pf = (t + 1 < ENT);
    const int k1 = (t + 1) * EBK;

    bf16x8 bfr[4][2];                             // B frags resident all tile
    #pragma unroll
    for (int q = 0; q < 4; ++q) {                 // 4 sub-phases x 16 MFMA
      if (q == 0) {
        #pragma unroll
        for (int j = 0; j < 4; ++j) {
          bfr[j][0] = *(const bf16x8*)&Bc[j * 1024 + s0];
          bfr[j][1] = *(const bf16x8*)&Bc[j * 1024 + s1];
        }
      }
      bf16x8 af[2][2];
      #pragma unroll
      for (int ii = 0; ii < 2; ++ii) {
        af[ii][0] = *(const bf16x8*)&Ac[(q * 2 + ii) * 1024 + s0];
        af[ii][1] = *(const bf16x8*)&Ac[(q * 2 + ii) * 1024 + s1];
      }
      if (pf) {                                   // spread stage issue (m196)
        if (q == 0) { stage_pair(c ^ 1, k1, 0); stage_pair(c ^ 1, k1, 1); }
        else if (q == 1) { stage_pair(c ^ 1, k1, 2); stage_pair(c ^ 1, k1, 3); }
      }
      __builtin_amdgcn_s_barrier();
      asm volatile("s_waitcnt lgkmcnt(0)" ::: "memory");
      __builtin_amdgcn_sched_barrier(0);          // rule #18: pin MFMA after wait
      __builtin_amdgcn_s_setprio(1);
      #pragma unroll
      for (int kk = 0; kk < 2; ++kk)
        #pragma unroll
        for (int ii = 0; ii < 2; ++ii)
          #pragma unroll
          for (int j = 0; j < 4; ++j)
            acc[q * 2 + ii][j] = __builtin_amdgcn_mfma_f32_16x16x32_bf16(
                af[ii][kk], bfr[j][kk], acc[q * 2 + ii][j], 0, 0, 0);
      __builtin_amdgcn_s_setprio(0);
      __builtin_amdgcn_s_barrier();
    }
  }

  // epilogue: C/D layout col = lane&15, row = quad*4 + reg
  const int g = (n0 + wn) >> 6;                   // channel group 0..15
  #pragma unroll
  for (int j = 0; j < 2; ++j) {
    const int d = g * 32 + j * 16 + l16;
    #pragma unroll
    for (int i = 0; i < 8; ++i) {
      #pragma unroll
      for (int r = 0; r < 4; ++r) {
        const int row = m0 + wm + i * 16 + quad * 4 + r;
        const long long off = ((long long)b * SEQ + row) * D_MODEL + d;
        const float num = acc[i][j][r];
        const float den = acc[i][j + 2][r];
        out[off] = (float)sigq[off] * (num / den);
      }
    }
  }
}

// ---------------------------------------------------------------- launch
extern "C" void kernel_launch(void* const* d_in, const int* in_sizes, int n_in,
                              void* d_out, int out_size, void* d_ws, size_t ws_size,
                              hipStream_t stream) {
  const float* inputs1 = (const float*)d_in[0];
  const float* inputs2 = (const float*)d_in[1];
  const float* Wq = (const float*)d_in[2];
  const float* bq = (const float*)d_in[3];
  const float* Wk = (const float*)d_in[4];
  const float* bk = (const float*)d_in[5];
  const float* Wv = (const float*)d_in[6];
  const float* bv = (const float*)d_in[7];
  const float* posb = (const float*)d_in[8];
  float* out = (float*)d_out;

  // workspace layout
  char* ws = (char*)d_ws;
  const long long szX  = (long long)ROWS * D_MODEL * 2;            // 16.78 MB
  const long long szW  = (long long)D_MODEL * D_MODEL * 2;         // 0.52 MB
  const long long szEB = (long long)SEQ * SEQ * 2;                 // 8.39 MB
  const long long szT  = (long long)BATCH * 2 * D_MODEL * SEQ * 2; // 33.55 MB
  __bf16* x1b   = (__bf16*)(ws);                 ws += szX;
  __bf16* x2b   = (__bf16*)(ws);                 ws += szX;
  __bf16* wb    = (__bf16*)(ws);                 ws += 3 * szW;
  __bf16* expBb = (__bf16*)(ws);                 ws += szEB;
  __bf16* sigq  = (__bf16*)(ws);                 ws += szX;
  __bf16* kT    = (__bf16*)(ws);                 ws += szX;
  __bf16* vT    = (__bf16*)(ws);                 ws += szX;
  __bf16* ekvT  = (__bf16*)(ws);                 ws += szT;

  // one-time: allow 128 KiB dynamic LDS for the einsum kernel
  static bool attr_done = false;
  if (!attr_done) {
    hipFuncSetAttribute((const void*)einsum_fused_kernel,
                        hipFuncAttributeMaxDynamicSharedMemorySize, 131072);
    attr_done = true;
  }

  // 1) all converts, one flat launch
  cvt_all_kernel<<<21248, 256, 0, stream>>>(inputs1, inputs2, posb,
                                            Wq, Wk, Wv,
                                            x1b, x2b, expBb, wb);

  // 2) tri-GEMM: q (row-major) + kT/vT (d-major), dbuf + phase-interleaved
  {
    dim3 g(ROWS / 256, D_MODEL / 128, 3);
    tri_gemm_kernel<<<g, 256, 0, stream>>>(x1b, x2b, wb, bq, bk, bv,
                                           sigq, kT, vT);
  }

  // 3) streaming combine -> ekvT grouped [b][1024][S]
  combine_kernel<<<(D_MODEL * ROWS / 8) / 256, 256, 0, stream>>>(kT, vT, ekvT);

  // 4) einsum + final fused: 256^2 tile, phase-interleaved staging
  {
    dim3 g(SEQ / EBM, (2 * D_MODEL) / EBN, BATCH);
    einsum_fused_kernel<<<g, 512, 131072, stream>>>(expBb, ekvT, sigq, out);
  }
}

// Round 3
// 254.119 us; speedup vs baseline: 1.0850x; 1.0850x over previous
//
#include <hip/hip_runtime.h>

typedef float  f32x4  __attribute__((ext_vector_type(4)));
typedef __bf16 bf16x8 __attribute__((ext_vector_type(8)));
typedef __bf16 bf16x4 __attribute__((ext_vector_type(4)));

#define D_MODEL 512
#define SEQ     2048
#define BATCH   8
#define ROWS    (BATCH * SEQ)   // 16384

// async 16B global -> LDS (each lane deposits at lds_base + lane*16B)
#define ASYNC_COPY16(dst_lds, src_glb)                                          \
  __builtin_amdgcn_global_load_lds(                                             \
      (const __attribute__((address_space(1))) void*)(src_glb),                 \
      (__attribute__((address_space(3))) void*)(dst_lds), 16, 0, 0)

// ------------------------------------------------------------ fused converts
__global__ void cvt_all_kernel(const float* __restrict__ x1,
                               const float* __restrict__ x2,
                               const float* __restrict__ posb,
                               const float* __restrict__ Wq,
                               const float* __restrict__ Wk,
                               const float* __restrict__ Wv,
                               __bf16* __restrict__ x1b, __bf16* __restrict__ x2b,
                               __bf16* __restrict__ expBb, __bf16* __restrict__ wb)
{
  const int blk = blockIdx.x;
  if (blk < 16384) {
    const float* in = (blk < 8192) ? x1 : x2;
    __bf16* out = (blk < 8192) ? x1b : x2b;
    const int i = (blk & 8191) * 256 + threadIdx.x;
    float4 v = ((const float4*)in)[i];
    bf16x4 o = { (__bf16)v.x, (__bf16)v.y, (__bf16)v.z, (__bf16)v.w };
    ((bf16x4*)out)[i] = o;
  } else if (blk < 20480) {
    const int i = (blk - 16384) * 256 + threadIdx.x;
    float4 v = ((const float4*)posb)[i];
    bf16x4 o = { (__bf16)__expf(v.x), (__bf16)__expf(v.y),
                 (__bf16)__expf(v.z), (__bf16)__expf(v.w) };
    ((bf16x4*)expBb)[i] = o;
  } else {
    const int i = (blk - 20480) * 256 + threadIdx.x;
    const int nW4 = D_MODEL * D_MODEL / 4;
    const float* src = (i < nW4) ? Wq : (i < 2 * nW4) ? Wk : Wv;
    const int ii = i - ((i < nW4) ? 0 : (i < 2 * nW4) ? nW4 : 2 * nW4);
    float4 v = ((const float4*)src)[ii];
    bf16x4 o = { (__bf16)v.x, (__bf16)v.y, (__bf16)v.z, (__bf16)v.w };
    ((bf16x4*)wb)[i] = o;
  }
}

// ------------------------------------------------------------- tri-GEMM v3
// Ported onto the PROVEN einsum structure (975 TF measured): 256x256 tile,
// BK=64, 512 threads (8 waves 2Mx4N), 128 KiB double-buffered dynamic LDS,
// phase-spread staging + counted-wait + raw-barrier + setprio schedule.
// K=512 -> 8 K-tiles. Grid (64, 2, 3):
// z=0: q    = x1*Wq^T  -> sigmoid -> sigq [rows][d]   (m=rows=L0, n=d=F0)
// z=1: kT   = Wk*x1^T  -> + bk    -> kT  [d][rows]    (m=d=F0, n=rows=L0)
// z=2: vT   = Wv*x2^T  -> + bv    -> vT  [d][rows]
#define TNT (D_MODEL / 64)   // 8 K-tiles

__global__ __launch_bounds__(512) void tri_gemm_kernel(
    const __bf16* __restrict__ x1b, const __bf16* __restrict__ x2b,
    const __bf16* __restrict__ wb,
    const float* __restrict__ bq, const float* __restrict__ bk,
    const float* __restrict__ bv,
    __bf16* __restrict__ sigq, __bf16* __restrict__ kT,
    __bf16* __restrict__ vT)
{
  extern __shared__ __align__(16) __bf16 smem[];  // A[2][16384] | B[2][16384]

  const int K = D_MODEL;
  const int z = blockIdx.z;
  const int tid  = threadIdx.x;
  const int wave = tid >> 6;
  const int lane = tid & 63;
  const int quad = lane >> 4;
  const int l16  = lane & 15;
  const int wm   = (wave >> 2) * 128;             // 2 wave-rows of 128
  const int wn   = (wave & 3) * 64;               // 4 wave-cols of 64
  const int L0   = blockIdx.x * 256;              // looped dim (rows)
  const int F0   = blockIdx.y * 256;              // fixed dim (d)
  const int m0   = (z == 0) ? L0 : F0;
  const int n0   = (z == 0) ? F0 : L0;
  const int l8r  = lane >> 3;
  const int scol = ((lane & 7) ^ l8r) * 8;        // pre-swizzled global col

  const __bf16* Ap = (z == 0) ? x1b
                   : (z == 1) ? (wb + (long long)D_MODEL * D_MODEL)
                              : (wb + 2LL * D_MODEL * D_MODEL);
  const __bf16* Bp = (z == 0) ? wb : (z == 1) ? x1b : x2b;

  const __bf16* gA = Ap + (long long)(m0 + wave * 8 + l8r) * K + scol;
  const __bf16* gB = Bp + (long long)(n0 + wave * 8 + l8r) * K + scol;
  __bf16* lA = smem +         (wave * 8) * 64;
  __bf16* lB = smem + 32768 + (wave * 8) * 64;

  f32x4 acc[8][4];
  #pragma unroll
  for (int i = 0; i < 8; ++i)
    #pragma unroll
    for (int j = 0; j < 4; ++j) acc[i][j] = (f32x4){0.f, 0.f, 0.f, 0.f};

  // pair i covers A rows [i*64,+64) and B rows [i*64,+64) of the 256 tile
  auto stage_pair = [&](int c, int k0, int i) {
    ASYNC_COPY16(lA + c * 16384 + i * 4096, gA + (long long)i * 64 * K + k0);
    ASYNC_COPY16(lB + c * 16384 + i * 4096, gB + (long long)i * 64 * K + k0);
  };

  #pragma unroll
  for (int i = 0; i < 4; ++i) stage_pair(0, 0, i);   // prologue burst (once)

  const int s0 = ((quad    ) ^ (l16 & 7)) * 8;    // k-slice 0 slot
  const int s1 = ((quad + 4) ^ (l16 & 7)) * 8;    // k-slice 1 slot

  for (int t = 0; t < TNT; ++t) {
    const int c = t & 1;
    asm volatile("s_waitcnt vmcnt(0)" ::: "memory");  // old loads only
    __builtin_amdgcn_s_barrier();                     // deposits visible
    __builtin_amdgcn_sched_barrier(0);

    const __bf16* Ac = smem +         c * 16384 + (wm + l16) * 64;
    const __bf16* Bc = smem + 32768 + c * 16384 + (wn + l16) * 64;
    const bool pf = (t + 1 < TNT);
    const int k1 = (t + 1) * 64;

    bf16x8 bfr[4][2];                             // B frags resident all tile
    #pragma unroll
    for (int q = 0; q < 4; ++q) {                 // 4 sub-phases x 16 MFMA
      if (q == 0) {
        #pragma unroll
        for (int j = 0; j < 4; ++j) {
          bfr[j][0] = *(const bf16x8*)&Bc[j * 1024 + s0];
          bfr[j][1] = *(const bf16x8*)&Bc[j * 1024 + s1];
        }
      }
      bf16x8 af[2][2];
      #pragma unroll
      for (int ii = 0; ii < 2; ++ii) {
        af[ii][0] = *(const bf16x8*)&Ac[(q * 2 + ii) * 1024 + s0];
        af[ii][1] = *(const bf16x8*)&Ac[(q * 2 + ii) * 1024 + s1];
      }
      if (pf) {                                   // spread stage issue (m196)
        if (q == 0) { stage_pair(c ^ 1, k1, 0); stage_pair(c ^ 1, k1, 1); }
        else if (q == 1) { stage_pair(c ^ 1, k1, 2); stage_pair(c ^ 1, k1, 3); }
      }
      __builtin_amdgcn_s_barrier();
      asm volatile("s_waitcnt lgkmcnt(0)" ::: "memory");
      __builtin_amdgcn_sched_barrier(0);          // rule #18: pin MFMA after wait
      __builtin_amdgcn_s_setprio(1);
      #pragma unroll
      for (int kk = 0; kk < 2; ++kk)
        #pragma unroll
        for (int ii = 0; ii < 2; ++ii)
          #pragma unroll
          for (int j = 0; j < 4; ++j)
            acc[q * 2 + ii][j] = __builtin_amdgcn_mfma_f32_16x16x32_bf16(
                af[ii][kk], bfr[j][kk], acc[q * 2 + ii][j], 0, 0, 0);
      __builtin_amdgcn_s_setprio(0);
      __builtin_amdgcn_s_barrier();
    }
  }

  // epilogue: C/D layout col = lane&15, row = quad*4 + reg
  if (z == 0) {
    #pragma unroll
    for (int j = 0; j < 4; ++j) {
      const int col = n0 + wn + j * 16 + l16;         // d
      const float bvv = bq[col];
      #pragma unroll
      for (int i = 0; i < 8; ++i) {
        #pragma unroll
        for (int r = 0; r < 4; ++r) {
          const int row = m0 + wm + i * 16 + quad * 4 + r;
          float x = acc[i][j][r] + bvv;
          sigq[(long long)row * D_MODEL + col] =
              (__bf16)(1.f / (1.f + __expf(-x)));
        }
      }
    }
  } else {
    const float* bias = (z == 1) ? bk : bv;
    __bf16* outp = (z == 1) ? kT : vT;
    #pragma unroll
    for (int i = 0; i < 8; ++i) {
      #pragma unroll
      for (int r = 0; r < 4; ++r) {
        const int d = m0 + wm + i * 16 + quad * 4 + r;
        const float bvv = bias[d];
        #pragma unroll
        for (int j = 0; j < 4; ++j) {
          const int rr = n0 + wn + j * 16 + l16;      // global row 0..16383
          outp[(long long)d * ROWS + rr] = (__bf16)(acc[i][j][r] + bvv);
        }
      }
    }
  }
}

// ------------------------------------------------------ streaming combine
__global__ __launch_bounds__(256) void combine_kernel(
    const __bf16* __restrict__ kT, const __bf16* __restrict__ vT,
    __bf16* __restrict__ ekvT)
{
  const int c = blockIdx.x * 256 + threadIdx.x;   // 16B chunk id, 0..2^20-1
  const int d   = c >> 11;                        // 2048 chunks per d-row
  const int off = (c & 2047) * 8;                 // position in 16384 rows
  const int b = off >> 11;
  const int s = off & 2047;

  bf16x8 kk = *(const bf16x8*)(kT + (long long)d * ROWS + off);
  bf16x8 vv = *(const bf16x8*)(vT + (long long)d * ROWS + off);
  bf16x8 ek, ev;
  #pragma unroll
  for (int e = 0; e < 8; ++e) {
    float ekf = __expf((float)kk[e]);
    ek[e] = (__bf16)ekf;
    ev[e] = (__bf16)(ekf * (float)vv[e]);
  }
  const int gr = ((d >> 5) << 6) + (d & 31);
  __bf16* outp = ekvT + (long long)b * (2 * D_MODEL) * SEQ + s;
  *(bf16x8*)(outp + (long long)gr * SEQ)        = ev;
  *(bf16x8*)(outp + (long long)(gr + 32) * SEQ) = ek;
}

// -------------------------------------------- einsum + final, fused epilogue
// 256x256 tile, BK=64, 8 waves (2Mx4N), double-buffered 128 KiB LDS.
// Staging for tile t+1 is SPREAD across tile t's phases (pairs {0,1} in
// phase 0, pairs {2,3} in phase 1), issued after that phase's ds_reads so
// VMEM issue hides under MFMA (m196 lesson).
#define EBM 256
#define EBN 256
#define EBK 64
#define ENT (SEQ / EBK)   // 32

__global__ __launch_bounds__(512) void einsum_fused_kernel(
    const __bf16* __restrict__ A, const __bf16* __restrict__ BtAll,
    const __bf16* __restrict__ sigq, float* __restrict__ out)
{
  extern __shared__ __align__(16) __bf16 smem[];  // A[2][16384] | B[2][16384]

  const int b = blockIdx.z;
  const __bf16* Bt = BtAll + (long long)b * (2 * D_MODEL) * SEQ;

  const int tid  = threadIdx.x;
  const int wave = tid >> 6;
  const int lane = tid & 63;
  const int quad = lane >> 4;
  const int l16  = lane & 15;
  const int wm   = (wave >> 2) * 128;             // 2 wave-rows of 128
  const int wn   = (wave & 3) * 64;               // 4 wave-cols of 64
  const int m0   = blockIdx.x * EBM;
  const int n0   = blockIdx.y * EBN;
  const int l8r  = lane >> 3;
  const int scol = ((lane & 7) ^ l8r) * 8;        // pre-swizzled global col

  const __bf16* gA = A  + (long long)(m0 + wave * 8 + l8r) * SEQ + scol;
  const __bf16* gB = Bt + (long long)(n0 + wave * 8 + l8r) * SEQ + scol;
  __bf16* lA = smem +         (wave * 8) * 64;
  __bf16* lB = smem + 32768 + (wave * 8) * 64;

  f32x4 acc[8][4];
  #pragma unroll
  for (int i = 0; i < 8; ++i)
    #pragma unroll
    for (int j = 0; j < 4; ++j) acc[i][j] = (f32x4){0.f, 0.f, 0.f, 0.f};

  // pair i covers A rows [i*64,+64) and B rows [i*64,+64) of the 256-row tile
  auto stage_pair = [&](int c, int k0, int i) {
    ASYNC_COPY16(lA + c * 16384 + i * 4096, gA + (long long)i * 64 * SEQ + k0);
    ASYNC_COPY16(lB + c * 16384 + i * 4096, gB + (long long)i * 64 * SEQ + k0);
  };

  #pragma unroll
  for (int i = 0; i < 4; ++i) stage_pair(0, 0, i);   // prologue burst (once)

  const int s0 = ((quad    ) ^ (l16 & 7)) * 8;    // k-slice 0 slot
  const int s1 = ((quad + 4) ^ (l16 & 7)) * 8;    // k-slice 1 slot

  for (int t = 0; t < ENT; ++t) {
    const int c = t & 1;
    asm volatile("s_waitcnt vmcnt(0)" ::: "memory");  // old loads only
    __builtin_amdgcn_s_barrier();                     // deposits visible
    __builtin_amdgcn_sched_barrier(0);

    const __bf16* Ac = smem +         c * 16384 + (wm + l16) * 64;
    const __bf16* Bc = smem + 32768 + c * 16384 + (wn + l16) * 64;
    const bool pf = (t + 1 < ENT);
    const int k1 = (t + 1) * EBK;

    bf16x8 bfr[4][2];                             // B frags resident all tile
    #pragma unroll
    for (int q = 0; q < 4; ++q) {                 // 4 sub-phases x 16 MFMA
      if (q == 0) {
        #pragma unroll
        for (int j = 0; j < 4; ++j) {
          bfr[j][0] = *(const bf16x8*)&Bc[j * 1024 + s0];
          bfr[j][1] = *(const bf16x8*)&Bc[j * 1024 + s1];
        }
      }
      bf16x8 af[2][2];
      #pragma unroll
      for (int ii = 0; ii < 2; ++ii) {
        af[ii][0] = *(const bf16x8*)&Ac[(q * 2 + ii) * 1024 + s0];
        af[ii][1] = *(const bf16x8*)&Ac[(q * 2 + ii) * 1024 + s1];
      }
      if (pf) {                                   // spread stage issue (m196)
        if (q == 0) { stage_pair(c ^ 1, k1, 0); stage_pair(c ^ 1, k1, 1); }
        else if (q == 1) { stage_pair(c ^ 1, k1, 2); stage_pair(c ^ 1, k1, 3); }
      }
      __builtin_amdgcn_s_barrier();
      asm volatile("s_waitcnt lgkmcnt(0)" ::: "memory");
      __builtin_amdgcn_sched_barrier(0);          // rule #18: pin MFMA after wait
      __builtin_amdgcn_s_setprio(1);
      #pragma unroll
      for (int kk = 0; kk < 2; ++kk)
        #pragma unroll
        for (int ii = 0; ii < 2; ++ii)
          #pragma unroll
          for (int j = 0; j < 4; ++j)
            acc[q * 2 + ii][j] = __builtin_amdgcn_mfma_f32_16x16x32_bf16(
                af[ii][kk], bfr[j][kk], acc[q * 2 + ii][j], 0, 0, 0);
      __builtin_amdgcn_s_setprio(0);
      __builtin_amdgcn_s_barrier();
    }
  }

  // epilogue: C/D layout col = lane&15, row = quad*4 + reg
  const int g = (n0 + wn) >> 6;                   // channel group 0..15
  #pragma unroll
  for (int j = 0; j < 2; ++j) {
    const int d = g * 32 + j * 16 + l16;
    #pragma unroll
    for (int i = 0; i < 8; ++i) {
      #pragma unroll
      for (int r = 0; r < 4; ++r) {
        const int row = m0 + wm + i * 16 + quad * 4 + r;
        const long long off = ((long long)b * SEQ + row) * D_MODEL + d;
        const float num = acc[i][j][r];
        const float den = acc[i][j + 2][r];
        out[off] = (float)sigq[off] * (num / den);
      }
    }
  }
}

// ---------------------------------------------------------------- launch
extern "C" void kernel_launch(void* const* d_in, const int* in_sizes, int n_in,
                              void* d_out, int out_size, void* d_ws, size_t ws_size,
                              hipStream_t stream) {
  const float* inputs1 = (const float*)d_in[0];
  const float* inputs2 = (const float*)d_in[1];
  const float* Wq = (const float*)d_in[2];
  const float* bq = (const float*)d_in[3];
  const float* Wk = (const float*)d_in[4];
  const float* bk = (const float*)d_in[5];
  const float* Wv = (const float*)d_in[6];
  const float* bv = (const float*)d_in[7];
  const float* posb = (const float*)d_in[8];
  float* out = (float*)d_out;

  // workspace layout
  char* ws = (char*)d_ws;
  const long long szX  = (long long)ROWS * D_MODEL * 2;            // 16.78 MB
  const long long szW  = (long long)D_MODEL * D_MODEL * 2;         // 0.52 MB
  const long long szEB = (long long)SEQ * SEQ * 2;                 // 8.39 MB
  const long long szT  = (long long)BATCH * 2 * D_MODEL * SEQ * 2; // 33.55 MB
  __bf16* x1b   = (__bf16*)(ws);                 ws += szX;
  __bf16* x2b   = (__bf16*)(ws);                 ws += szX;
  __bf16* wb    = (__bf16*)(ws);                 ws += 3 * szW;
  __bf16* expBb = (__bf16*)(ws);                 ws += szEB;
  __bf16* sigq  = (__bf16*)(ws);                 ws += szX;
  __bf16* kT    = (__bf16*)(ws);                 ws += szX;
  __bf16* vT    = (__bf16*)(ws);                 ws += szX;
  __bf16* ekvT  = (__bf16*)(ws);                 ws += szT;

  // one-time: allow 128 KiB dynamic LDS for the big-tile kernels
  static bool attr_done = false;
  if (!attr_done) {
    hipFuncSetAttribute((const void*)einsum_fused_kernel,
                        hipFuncAttributeMaxDynamicSharedMemorySize, 131072);
    hipFuncSetAttribute((const void*)tri_gemm_kernel,
                        hipFuncAttributeMaxDynamicSharedMemorySize, 131072);
    attr_done = true;
  }

  // 1) all converts, one flat launch
  cvt_all_kernel<<<21248, 256, 0, stream>>>(inputs1, inputs2, posb,
                                            Wq, Wk, Wv,
                                            x1b, x2b, expBb, wb);

  // 2) tri-GEMM: 256^2 einsum-structure, grid (rows/256, d/256, 3)
  {
    dim3 g(ROWS / 256, D_MODEL / 256, 3);
    tri_gemm_kernel<<<g, 512, 131072, stream>>>(x1b, x2b, wb, bq, bk, bv,
                                                sigq, kT, vT);
  }

  // 3) streaming combine -> ekvT grouped [b][1024][S]
  combine_kernel<<<(D_MODEL * ROWS / 8) / 256, 256, 0, stream>>>(kT, vT, ekvT);

  // 4) einsum + final fused: 256^2 tile, phase-interleaved staging
  {
    dim3 g(SEQ / EBM, (2 * D_MODEL) / EBN, BATCH);
    einsum_fused_kernel<<<g, 512, 131072, stream>>>(expBb, ekvT, sigq, out);
  }
}

// Round 4
// 243.839 us; speedup vs baseline: 1.1308x; 1.0422x over previous
//
#include <hip/hip_runtime.h>

typedef float  f32x4  __attribute__((ext_vector_type(4)));
typedef __bf16 bf16x8 __attribute__((ext_vector_type(8)));
typedef __bf16 bf16x4 __attribute__((ext_vector_type(4)));

#define D_MODEL 512
#define SEQ     2048
#define BATCH   8
#define ROWS    (BATCH * SEQ)   // 16384

// async 16B global -> LDS (each lane deposits at lds_base + lane*16B)
#define ASYNC_COPY16(dst_lds, src_glb)                                          \
  __builtin_amdgcn_global_load_lds(                                             \
      (const __attribute__((address_space(1))) void*)(src_glb),                 \
      (__attribute__((address_space(3))) void*)(dst_lds), 16, 0, 0)

// ------------------------------------------------------------ fused converts
__global__ void cvt_all_kernel(const float* __restrict__ x1,
                               const float* __restrict__ x2,
                               const float* __restrict__ posb,
                               const float* __restrict__ Wq,
                               const float* __restrict__ Wk,
                               const float* __restrict__ Wv,
                               __bf16* __restrict__ x1b, __bf16* __restrict__ x2b,
                               __bf16* __restrict__ expBb, __bf16* __restrict__ wb)
{
  const int blk = blockIdx.x;
  if (blk < 16384) {
    const float* in = (blk < 8192) ? x1 : x2;
    __bf16* out = (blk < 8192) ? x1b : x2b;
    const int i = (blk & 8191) * 256 + threadIdx.x;
    float4 v = ((const float4*)in)[i];
    bf16x4 o = { (__bf16)v.x, (__bf16)v.y, (__bf16)v.z, (__bf16)v.w };
    ((bf16x4*)out)[i] = o;
  } else if (blk < 20480) {
    const int i = (blk - 16384) * 256 + threadIdx.x;
    float4 v = ((const float4*)posb)[i];
    bf16x4 o = { (__bf16)__expf(v.x), (__bf16)__expf(v.y),
                 (__bf16)__expf(v.z), (__bf16)__expf(v.w) };
    ((bf16x4*)expBb)[i] = o;
  } else {
    const int i = (blk - 20480) * 256 + threadIdx.x;
    const int nW4 = D_MODEL * D_MODEL / 4;
    const float* src = (i < nW4) ? Wq : (i < 2 * nW4) ? Wk : Wv;
    const int ii = i - ((i < nW4) ? 0 : (i < 2 * nW4) ? nW4 : 2 * nW4);
    float4 v = ((const float4*)src)[ii];
    bf16x4 o = { (__bf16)v.x, (__bf16)v.y, (__bf16)v.z, (__bf16)v.w };
    ((bf16x4*)wb)[i] = o;
  }
}

// ------------------------------------------------------------- q GEMM
// q = sigmoid(x1*Wq^T + bq) -> sigq [rows][d], bf16.
// Tile 256(rows) x 128(d), BK=64, 8 waves 4Mx2N, 96 KiB dbuf dynamic LDS.
// Grid (64,4) = 256 blocks = full chip. Schedule = proven einsum template.
__global__ __launch_bounds__(512) void q_gemm_kernel(
    const __bf16* __restrict__ x1b, const __bf16* __restrict__ wb,
    const float* __restrict__ bq, __bf16* __restrict__ sigq)
{
  extern __shared__ __align__(16) __bf16 smem[];  // A[2][16384] | B[2][8192]

  const int K = D_MODEL;
  const int tid  = threadIdx.x;
  const int wave = tid >> 6;
  const int lane = tid & 63;
  const int quad = lane >> 4;
  const int l16  = lane & 15;
  const int wm   = (wave >> 1) * 64;   // 4 M-waves x 64 rows
  const int wn   = (wave & 1) * 64;    // 2 N-waves x 64 d
  const int m0   = blockIdx.x * 256;   // rows tile
  const int n0   = blockIdx.y * 128;   // d tile
  const int l8r  = lane >> 3;
  const int scol = ((lane & 7) ^ l8r) * 8;        // pre-swizzled global col

  const __bf16* ga[4]; const __bf16* gb[2];
  #pragma unroll
  for (int i = 0; i < 4; ++i)
    ga[i] = x1b + (long long)(m0 + i * 64 + wave * 8 + l8r) * K + scol;
  #pragma unroll
  for (int i = 0; i < 2; ++i)
    gb[i] = wb + (long long)(n0 + i * 64 + wave * 8 + l8r) * K + scol;

  f32x4 acc[4][4];
  #pragma unroll
  for (int i = 0; i < 4; ++i)
    #pragma unroll
    for (int j = 0; j < 4; ++j) acc[i][j] = (f32x4){0.f, 0.f, 0.f, 0.f};

  auto stageA2 = [&](int c, int k0, int i0) {     // 2 A chunks (rows i0*64..)
    ASYNC_COPY16(smem + c * 16384 + (i0 * 64 + wave * 8) * 64, ga[i0] + k0);
    ASYNC_COPY16(smem + c * 16384 + ((i0 + 1) * 64 + wave * 8) * 64, ga[i0 + 1] + k0);
  };
  auto stageB1 = [&](int c, int k0, int i) {      // 1 B chunk
    ASYNC_COPY16(smem + 32768 + c * 8192 + (i * 64 + wave * 8) * 64, gb[i] + k0);
  };

  stageA2(0, 0, 0); stageA2(0, 0, 2);
  stageB1(0, 0, 0); stageB1(0, 0, 1);             // prologue (6 loads)

  const int s0 = ((quad    ) ^ (l16 & 7)) * 8;
  const int s1 = ((quad + 4) ^ (l16 & 7)) * 8;

  for (int t = 0; t < 8; ++t) {
    const int c = t & 1;
    asm volatile("s_waitcnt vmcnt(0)" ::: "memory");  // old loads only
    __builtin_amdgcn_s_barrier();
    __builtin_amdgcn_sched_barrier(0);

    const __bf16* Ac = smem +         c * 16384 + (wm + l16) * 64;
    const __bf16* Bc = smem + 32768 + c * 8192  + (wn + l16) * 64;
    const bool pf = (t + 1 < 8);
    const int k1 = (t + 1) * 64;

    bf16x8 bfr[4][2];                             // B frags resident all tile
    #pragma unroll
    for (int p = 0; p < 2; ++p) {                 // 2 sub-phases x 16 MFMA
      if (p == 0) {
        #pragma unroll
        for (int j = 0; j < 4; ++j) {
          bfr[j][0] = *(const bf16x8*)&Bc[j * 1024 + s0];
          bfr[j][1] = *(const bf16x8*)&Bc[j * 1024 + s1];
        }
      }
      bf16x8 af[2][2];
      #pragma unroll
      for (int ii = 0; ii < 2; ++ii) {
        af[ii][0] = *(const bf16x8*)&Ac[(p * 2 + ii) * 1024 + s0];
        af[ii][1] = *(const bf16x8*)&Ac[(p * 2 + ii) * 1024 + s1];
      }
      if (pf) {                                   // spread stage issue (m196)
        if (p == 0) { stageA2(c ^ 1, k1, 0); stageB1(c ^ 1, k1, 0); }
        else        { stageA2(c ^ 1, k1, 2); stageB1(c ^ 1, k1, 1); }
      }
      __builtin_amdgcn_s_barrier();
      asm volatile("s_waitcnt lgkmcnt(0)" ::: "memory");
      __builtin_amdgcn_sched_barrier(0);          // rule #18
      __builtin_amdgcn_s_setprio(1);
      #pragma unroll
      for (int kk = 0; kk < 2; ++kk)
        #pragma unroll
        for (int ii = 0; ii < 2; ++ii)
          #pragma unroll
          for (int j = 0; j < 4; ++j)
            acc[p * 2 + ii][j] = __builtin_amdgcn_mfma_f32_16x16x32_bf16(
                af[ii][kk], bfr[j][kk], acc[p * 2 + ii][j], 0, 0, 0);
      __builtin_amdgcn_s_setprio(0);
      __builtin_amdgcn_s_barrier();
    }
  }

  // epilogue: C/D layout col = lane&15 (d), row = quad*4 + reg (rows)
  #pragma unroll
  for (int j = 0; j < 4; ++j) {
    const int col = n0 + wn + j * 16 + l16;       // d
    const float bvv = bq[col];
    #pragma unroll
    for (int i = 0; i < 4; ++i) {
      #pragma unroll
      for (int r = 0; r < 4; ++r) {
        const int row = m0 + wm + i * 16 + quad * 4 + r;
        float x = acc[i][j][r] + bvv;
        sigq[(long long)row * D_MODEL + col] = (__bf16)(1.f / (1.f + __expf(-x)));
      }
    }
  }
}

// ------------------------------------------------------------- kv fused GEMM
// One block computes BOTH kT and vT tiles for the same (d-tile, row-tile),
// then fuses exp(k)/exp(k)*v in the epilogue and writes ekvT grouped layout
// directly -> combine kernel eliminated (saves ~67 MB HBM round trip).
// Packed LDS rows: W-buf [256][64]: cols0-31 = Wk k-slice, 32-63 = Wv.
//                  X-buf [128][64]: cols0-31 = x1,         32-63 = x2.
// The standard XOR swizzle carries the per-lane source select automatically:
// content(slot c, row r) = global col-slot c^(r&7); read slot s0 -> Wk/x1
// fragment (cols 0-31), s1 -> Wv/x2 (cols 32-63). K advances 32/step, 16 steps.
// Tile 256(d) x 128(rows), 8 waves 4Mx2N, 96 KiB dbuf. Grid (128,2) = 256.
__global__ __launch_bounds__(512) void kv_fused_kernel(
    const __bf16* __restrict__ x1b, const __bf16* __restrict__ x2b,
    const __bf16* __restrict__ wb,
    const float* __restrict__ bk, const float* __restrict__ bv,
    __bf16* __restrict__ ekvT)
{
  extern __shared__ __align__(16) __bf16 smem[];  // W[2][16384] | X[2][8192]

  const int K = D_MODEL;
  const int tid  = threadIdx.x;
  const int wave = tid >> 6;
  const int lane = tid & 63;
  const int quad = lane >> 4;
  const int l16  = lane & 15;
  const int wm   = (wave >> 1) * 64;   // 4 M-waves x 64 d
  const int wn   = (wave & 1) * 64;    // 2 N-waves x 64 rows
  const int F0   = blockIdx.y * 256;   // d tile
  const int L0   = blockIdx.x * 128;   // rows tile
  const int l8r  = lane >> 3;
  const int scol = ((lane & 7) ^ l8r) * 8;
  const bool hi  = (scol >= 32);                  // this lane feeds Wv/x2 half
  const int sc   = scol & 31;

  const __bf16* Wkb = wb + (long long)D_MODEL * D_MODEL;
  const __bf16* Wvb = wb + 2LL * D_MODEL * D_MODEL;

  const __bf16* gW[4]; const __bf16* gX[2];
  #pragma unroll
  for (int i = 0; i < 4; ++i)
    gW[i] = (hi ? Wvb : Wkb) + (long long)(F0 + i * 64 + wave * 8 + l8r) * K + sc;
  #pragma unroll
  for (int i = 0; i < 2; ++i)
    gX[i] = (hi ? x2b : x1b) + (long long)(L0 + i * 64 + wave * 8 + l8r) * K + sc;

  f32x4 acck[4][4], accv[4][4];
  #pragma unroll
  for (int i = 0; i < 4; ++i)
    #pragma unroll
    for (int j = 0; j < 4; ++j) {
      acck[i][j] = (f32x4){0.f, 0.f, 0.f, 0.f};
      accv[i][j] = (f32x4){0.f, 0.f, 0.f, 0.f};
    }

  auto stageW = [&](int c, int k0) {              // 4 loads
    #pragma unroll
    for (int i = 0; i < 4; ++i)
      ASYNC_COPY16(smem + c * 16384 + (i * 64 + wave * 8) * 64, gW[i] + k0);
  };
  auto stageX = [&](int c, int k0) {              // 2 loads
    #pragma unroll
    for (int i = 0; i < 2; ++i)
      ASYNC_COPY16(smem + 32768 + c * 8192 + (i * 64 + wave * 8) * 64, gX[i] + k0);
  };

  stageW(0, 0); stageX(0, 0);                     // prologue (6 loads)

  const int s0 = ((quad    ) ^ (l16 & 7)) * 8;    // -> Wk / x1 fragment
  const int s1 = ((quad + 4) ^ (l16 & 7)) * 8;    // -> Wv / x2 fragment

  for (int s = 0; s < 16; ++s) {                  // K step = 32
    const int c = s & 1;
    asm volatile("s_waitcnt vmcnt(0)" ::: "memory");
    __builtin_amdgcn_s_barrier();
    __builtin_amdgcn_sched_barrier(0);

    const __bf16* Wc = smem +         c * 16384 + (wm + l16) * 64;
    const __bf16* Xc = smem + 32768 + c * 8192  + (wn + l16) * 64;
    const bool pf = (s + 1 < 16);
    const int k1 = (s + 1) * 32;

    // ---- phase A: k-GEMM (slots s0)
    {
      bf16x8 af[4], bfr[4];
      #pragma unroll
      for (int i = 0; i < 4; ++i) af[i]  = *(const bf16x8*)&Wc[i * 1024 + s0];
      #pragma unroll
      for (int j = 0; j < 4; ++j) bfr[j] = *(const bf16x8*)&Xc[j * 1024 + s0];
      if (pf) stageW(c ^ 1, k1);
      __builtin_amdgcn_s_barrier();
      asm volatile("s_waitcnt lgkmcnt(0)" ::: "memory");
      __builtin_amdgcn_sched_barrier(0);
      __builtin_amdgcn_s_setprio(1);
      #pragma unroll
      for (int i = 0; i < 4; ++i)
        #pragma unroll
        for (int j = 0; j < 4; ++j)
          acck[i][j] = __builtin_amdgcn_mfma_f32_16x16x32_bf16(
              af[i], bfr[j], acck[i][j], 0, 0, 0);
      __builtin_amdgcn_s_setprio(0);
      __builtin_amdgcn_s_barrier();
    }
    // ---- phase B: v-GEMM (slots s1)
    {
      bf16x8 af[4], bfr[4];
      #pragma unroll
      for (int i = 0; i < 4; ++i) af[i]  = *(const bf16x8*)&Wc[i * 1024 + s1];
      #pragma unroll
      for (int j = 0; j < 4; ++j) bfr[j] = *(const bf16x8*)&Xc[j * 1024 + s1];
      if (pf) stageX(c ^ 1, k1);
      __builtin_amdgcn_s_barrier();
      asm volatile("s_waitcnt lgkmcnt(0)" ::: "memory");
      __builtin_amdgcn_sched_barrier(0);
      __builtin_amdgcn_s_setprio(1);
      #pragma unroll
      for (int i = 0; i < 4; ++i)
        #pragma unroll
        for (int j = 0; j < 4; ++j)
          accv[i][j] = __builtin_amdgcn_mfma_f32_16x16x32_bf16(
              af[i], bfr[j], accv[i][j], 0, 0, 0);
      __builtin_amdgcn_s_setprio(0);
      __builtin_amdgcn_s_barrier();
    }
  }

  // epilogue: d = m (quad*4+reg), rows = n (lane&15); fuse exp and write
  // grouped ekvT: g=d>>5, w=d&31: row g*64+w = ek*v, row g*64+32+w = ek.
  const int b   = L0 >> 11;                       // batch (L0 mult of 128)
  const int sb  = L0 & 2047;                      // seq base within batch
  __bf16* outb = ekvT + (long long)b * (2 * D_MODEL) * SEQ + sb;
  #pragma unroll
  for (int i = 0; i < 4; ++i) {
    #pragma unroll
    for (int r = 0; r < 4; ++r) {
      const int d = F0 + wm + i * 16 + quad * 4 + r;
      const float bkd = bk[d];
      const float bvd = bv[d];
      const int gr = ((d >> 5) << 6) + (d & 31);
      #pragma unroll
      for (int j = 0; j < 4; ++j) {
        const int ss = wn + j * 16 + l16;         // seq offset within tile
        const float kkv = acck[i][j][r] + bkd;
        const float vvv = accv[i][j][r] + bvd;
        const float ekf = __expf(kkv);
        outb[(long long)gr * SEQ + ss]        = (__bf16)(ekf * vvv);
        outb[(long long)(gr + 32) * SEQ + ss] = (__bf16)ekf;
      }
    }
  }
}

// -------------------------------------------- einsum + final, fused epilogue
// 256x256 tile, BK=64, 8 waves (2Mx4N), double-buffered 128 KiB LDS.
#define EBM 256
#define EBN 256
#define EBK 64
#define ENT (SEQ / EBK)   // 32

__global__ __launch_bounds__(512) void einsum_fused_kernel(
    const __bf16* __restrict__ A, const __bf16* __restrict__ BtAll,
    const __bf16* __restrict__ sigq, float* __restrict__ out)
{
  extern __shared__ __align__(16) __bf16 smem[];  // A[2][16384] | B[2][16384]

  const int b = blockIdx.z;
  const __bf16* Bt = BtAll + (long long)b * (2 * D_MODEL) * SEQ;

  const int tid  = threadIdx.x;
  const int wave = tid >> 6;
  const int lane = tid & 63;
  const int quad = lane >> 4;
  const int l16  = lane & 15;
  const int wm   = (wave >> 2) * 128;             // 2 wave-rows of 128
  const int wn   = (wave & 3) * 64;               // 4 wave-cols of 64
  const int m0   = blockIdx.x * EBM;
  const int n0   = blockIdx.y * EBN;
  const int l8r  = lane >> 3;
  const int scol = ((lane & 7) ^ l8r) * 8;        // pre-swizzled global col

  const __bf16* gA = A  + (long long)(m0 + wave * 8 + l8r) * SEQ + scol;
  const __bf16* gB = Bt + (long long)(n0 + wave * 8 + l8r) * SEQ + scol;
  __bf16* lA = smem +         (wave * 8) * 64;
  __bf16* lB = smem + 32768 + (wave * 8) * 64;

  f32x4 acc[8][4];
  #pragma unroll
  for (int i = 0; i < 8; ++i)
    #pragma unroll
    for (int j = 0; j < 4; ++j) acc[i][j] = (f32x4){0.f, 0.f, 0.f, 0.f};

  auto stage_pair = [&](int c, int k0, int i) {
    ASYNC_COPY16(lA + c * 16384 + i * 4096, gA + (long long)i * 64 * SEQ + k0);
    ASYNC_COPY16(lB + c * 16384 + i * 4096, gB + (long long)i * 64 * SEQ + k0);
  };

  #pragma unroll
  for (int i = 0; i < 4; ++i) stage_pair(0, 0, i);   // prologue burst (once)

  const int s0 = ((quad    ) ^ (l16 & 7)) * 8;    // k-slice 0 slot
  const int s1 = ((quad + 4) ^ (l16 & 7)) * 8;    // k-slice 1 slot

  for (int t = 0; t < ENT; ++t) {
    const int c = t & 1;
    asm volatile("s_waitcnt vmcnt(0)" ::: "memory");  // old loads only
    __builtin_amdgcn_s_barrier();                     // deposits visible
    __builtin_amdgcn_sched_barrier(0);

    const __bf16* Ac = smem +         c * 16384 + (wm + l16) * 64;
    const __bf16* Bc = smem + 32768 + c * 16384 + (wn + l16) * 64;
    const bool pf = (t + 1 < ENT);
    const int k1 = (t + 1) * EBK;

    bf16x8 bfr[4][2];                             // B frags resident all tile
    #pragma unroll
    for (int q = 0; q < 4; ++q) {                 // 4 sub-phases x 16 MFMA
      if (q == 0) {
        #pragma unroll
        for (int j = 0; j < 4; ++j) {
          bfr[j][0] = *(const bf16x8*)&Bc[j * 1024 + s0];
          bfr[j][1] = *(const bf16x8*)&Bc[j * 1024 + s1];
        }
      }
      bf16x8 af[2][2];
      #pragma unroll
      for (int ii = 0; ii < 2; ++ii) {
        af[ii][0] = *(const bf16x8*)&Ac[(q * 2 + ii) * 1024 + s0];
        af[ii][1] = *(const bf16x8*)&Ac[(q * 2 + ii) * 1024 + s1];
      }
      if (pf) {                                   // spread stage issue (m196)
        if (q == 0) { stage_pair(c ^ 1, k1, 0); stage_pair(c ^ 1, k1, 1); }
        else if (q == 1) { stage_pair(c ^ 1, k1, 2); stage_pair(c ^ 1, k1, 3); }
      }
      __builtin_amdgcn_s_barrier();
      asm volatile("s_waitcnt lgkmcnt(0)" ::: "memory");
      __builtin_amdgcn_sched_barrier(0);          // rule #18: pin MFMA after wait
      __builtin_amdgcn_s_setprio(1);
      #pragma unroll
      for (int kk = 0; kk < 2; ++kk)
        #pragma unroll
        for (int ii = 0; ii < 2; ++ii)
          #pragma unroll
          for (int j = 0; j < 4; ++j)
            acc[q * 2 + ii][j] = __builtin_amdgcn_mfma_f32_16x16x32_bf16(
                af[ii][kk], bfr[j][kk], acc[q * 2 + ii][j], 0, 0, 0);
      __builtin_amdgcn_s_setprio(0);
      __builtin_amdgcn_s_barrier();
    }
  }

  // epilogue: C/D layout col = lane&15, row = quad*4 + reg
  const int g = (n0 + wn) >> 6;                   // channel group 0..15
  #pragma unroll
  for (int j = 0; j < 2; ++j) {
    const int d = g * 32 + j * 16 + l16;
    #pragma unroll
    for (int i = 0; i < 8; ++i) {
      #pragma unroll
      for (int r = 0; r < 4; ++r) {
        const int row = m0 + wm + i * 16 + quad * 4 + r;
        const long long off = ((long long)b * SEQ + row) * D_MODEL + d;
        const float num = acc[i][j][r];
        const float den = acc[i][j + 2][r];
        out[off] = (float)sigq[off] * (num / den);
      }
    }
  }
}

// ---------------------------------------------------------------- launch
extern "C" void kernel_launch(void* const* d_in, const int* in_sizes, int n_in,
                              void* d_out, int out_size, void* d_ws, size_t ws_size,
                              hipStream_t stream) {
  const float* inputs1 = (const float*)d_in[0];
  const float* inputs2 = (const float*)d_in[1];
  const float* Wq = (const float*)d_in[2];
  const float* bq = (const float*)d_in[3];
  const float* Wk = (const float*)d_in[4];
  const float* bk = (const float*)d_in[5];
  const float* Wv = (const float*)d_in[6];
  const float* bv = (const float*)d_in[7];
  const float* posb = (const float*)d_in[8];
  float* out = (float*)d_out;

  // workspace layout
  char* ws = (char*)d_ws;
  const long long szX  = (long long)ROWS * D_MODEL * 2;            // 16.78 MB
  const long long szW  = (long long)D_MODEL * D_MODEL * 2;         // 0.52 MB
  const long long szEB = (long long)SEQ * SEQ * 2;                 // 8.39 MB
  const long long szT  = (long long)BATCH * 2 * D_MODEL * SEQ * 2; // 33.55 MB
  __bf16* x1b   = (__bf16*)(ws);                 ws += szX;
  __bf16* x2b   = (__bf16*)(ws);                 ws += szX;
  __bf16* wb    = (__bf16*)(ws);                 ws += 3 * szW;
  __bf16* expBb = (__bf16*)(ws);                 ws += szEB;
  __bf16* sigq  = (__bf16*)(ws);                 ws += szX;
  __bf16* ekvT  = (__bf16*)(ws);                 ws += szT;

  // one-time: allow big dynamic LDS for the tile kernels
  static bool attr_done = false;
  if (!attr_done) {
    hipFuncSetAttribute((const void*)einsum_fused_kernel,
                        hipFuncAttributeMaxDynamicSharedMemorySize, 131072);
    hipFuncSetAttribute((const void*)q_gemm_kernel,
                        hipFuncAttributeMaxDynamicSharedMemorySize, 98304);
    hipFuncSetAttribute((const void*)kv_fused_kernel,
                        hipFuncAttributeMaxDynamicSharedMemorySize, 98304);
    attr_done = true;
  }

  // 1) all converts, one flat launch
  cvt_all_kernel<<<21248, 256, 0, stream>>>(inputs1, inputs2, posb,
                                            Wq, Wk, Wv,
                                            x1b, x2b, expBb, wb);

  // 2a) q GEMM: 256x128 tiles, grid (64,4) = 256 blocks
  {
    dim3 g(ROWS / 256, D_MODEL / 128);
    q_gemm_kernel<<<g, 512, 98304, stream>>>(x1b, wb, bq, sigq);
  }

  // 2b) kv fused GEMM + exp combine: 256(d)x128(rows), grid (128,2) = 256
  {
    dim3 g(ROWS / 128, D_MODEL / 256);
    kv_fused_kernel<<<g, 512, 98304, stream>>>(x1b, x2b, wb, bk, bv, ekvT);
  }

  // 3) einsum + final fused: 256^2 tile, phase-interleaved staging
  {
    dim3 g(SEQ / EBM, (2 * D_MODEL) / EBN, BATCH);
    einsum_fused_kernel<<<g, 512, 131072, stream>>>(expBb, ekvT, sigq, out);
  }
}

// Round 5
// 242.753 us; speedup vs baseline: 1.1358x; 1.0045x over previous
//
#include <hip/hip_runtime.h>

typedef float  f32x4  __attribute__((ext_vector_type(4)));
typedef __bf16 bf16x8 __attribute__((ext_vector_type(8)));
typedef __bf16 bf16x4 __attribute__((ext_vector_type(4)));

#define D_MODEL 512
#define SEQ     2048
#define BATCH   8
#define ROWS    (BATCH * SEQ)   // 16384

// async 16B global -> LDS (each lane deposits at lds_base + lane*16B)
#define ASYNC_COPY16(dst_lds, src_glb)                                          \
  __builtin_amdgcn_global_load_lds(                                             \
      (const __attribute__((address_space(1))) void*)(src_glb),                 \
      (__attribute__((address_space(3))) void*)(dst_lds), 16, 0, 0)

// ------------------------------------------------------------ fused converts
__global__ void cvt_all_kernel(const float* __restrict__ x1,
                               const float* __restrict__ x2,
                               const float* __restrict__ posb,
                               const float* __restrict__ Wq,
                               const float* __restrict__ Wk,
                               const float* __restrict__ Wv,
                               __bf16* __restrict__ x1b, __bf16* __restrict__ x2b,
                               __bf16* __restrict__ expBb, __bf16* __restrict__ wb)
{
  const int blk = blockIdx.x;
  if (blk < 16384) {
    const float* in = (blk < 8192) ? x1 : x2;
    __bf16* out = (blk < 8192) ? x1b : x2b;
    const int i = (blk & 8191) * 256 + threadIdx.x;
    float4 v = ((const float4*)in)[i];
    bf16x4 o = { (__bf16)v.x, (__bf16)v.y, (__bf16)v.z, (__bf16)v.w };
    ((bf16x4*)out)[i] = o;
  } else if (blk < 20480) {
    const int i = (blk - 16384) * 256 + threadIdx.x;
    float4 v = ((const float4*)posb)[i];
    bf16x4 o = { (__bf16)__expf(v.x), (__bf16)__expf(v.y),
                 (__bf16)__expf(v.z), (__bf16)__expf(v.w) };
    ((bf16x4*)expBb)[i] = o;
  } else {
    const int i = (blk - 20480) * 256 + threadIdx.x;
    const int nW4 = D_MODEL * D_MODEL / 4;
    const float* src = (i < nW4) ? Wq : (i < 2 * nW4) ? Wk : Wv;
    const int ii = i - ((i < nW4) ? 0 : (i < 2 * nW4) ? nW4 : 2 * nW4);
    float4 v = ((const float4*)src)[ii];
    bf16x4 o = { (__bf16)v.x, (__bf16)v.y, (__bf16)v.z, (__bf16)v.w };
    ((bf16x4*)wb)[i] = o;
  }
}

// ------------------------------------------------------------- q GEMM
// q = sigmoid(x1*Wq^T + bq) -> sigq [rows][d], bf16.   (unchanged, round-3)
__global__ __launch_bounds__(512) void q_gemm_kernel(
    const __bf16* __restrict__ x1b, const __bf16* __restrict__ wb,
    const float* __restrict__ bq, __bf16* __restrict__ sigq)
{
  extern __shared__ __align__(16) __bf16 smem[];  // A[2][16384] | B[2][8192]

  const int K = D_MODEL;
  const int tid  = threadIdx.x;
  const int wave = tid >> 6;
  const int lane = tid & 63;
  const int quad = lane >> 4;
  const int l16  = lane & 15;
  const int wm   = (wave >> 1) * 64;   // 4 M-waves x 64 rows
  const int wn   = (wave & 1) * 64;    // 2 N-waves x 64 d
  const int m0   = blockIdx.x * 256;   // rows tile
  const int n0   = blockIdx.y * 128;   // d tile
  const int l8r  = lane >> 3;
  const int scol = ((lane & 7) ^ l8r) * 8;        // pre-swizzled global col

  const __bf16* ga[4]; const __bf16* gb[2];
  #pragma unroll
  for (int i = 0; i < 4; ++i)
    ga[i] = x1b + (long long)(m0 + i * 64 + wave * 8 + l8r) * K + scol;
  #pragma unroll
  for (int i = 0; i < 2; ++i)
    gb[i] = wb + (long long)(n0 + i * 64 + wave * 8 + l8r) * K + scol;

  f32x4 acc[4][4];
  #pragma unroll
  for (int i = 0; i < 4; ++i)
    #pragma unroll
    for (int j = 0; j < 4; ++j) acc[i][j] = (f32x4){0.f, 0.f, 0.f, 0.f};

  auto stageA2 = [&](int c, int k0, int i0) {
    ASYNC_COPY16(smem + c * 16384 + (i0 * 64 + wave * 8) * 64, ga[i0] + k0);
    ASYNC_COPY16(smem + c * 16384 + ((i0 + 1) * 64 + wave * 8) * 64, ga[i0 + 1] + k0);
  };
  auto stageB1 = [&](int c, int k0, int i) {
    ASYNC_COPY16(smem + 32768 + c * 8192 + (i * 64 + wave * 8) * 64, gb[i] + k0);
  };

  stageA2(0, 0, 0); stageA2(0, 0, 2);
  stageB1(0, 0, 0); stageB1(0, 0, 1);             // prologue (6 loads)

  const int s0 = ((quad    ) ^ (l16 & 7)) * 8;
  const int s1 = ((quad + 4) ^ (l16 & 7)) * 8;

  for (int t = 0; t < 8; ++t) {
    const int c = t & 1;
    asm volatile("s_waitcnt vmcnt(0)" ::: "memory");
    __builtin_amdgcn_s_barrier();
    __builtin_amdgcn_sched_barrier(0);

    const __bf16* Ac = smem +         c * 16384 + (wm + l16) * 64;
    const __bf16* Bc = smem + 32768 + c * 8192  + (wn + l16) * 64;
    const bool pf = (t + 1 < 8);
    const int k1 = (t + 1) * 64;

    bf16x8 bfr[4][2];
    #pragma unroll
    for (int p = 0; p < 2; ++p) {
      if (p == 0) {
        #pragma unroll
        for (int j = 0; j < 4; ++j) {
          bfr[j][0] = *(const bf16x8*)&Bc[j * 1024 + s0];
          bfr[j][1] = *(const bf16x8*)&Bc[j * 1024 + s1];
        }
      }
      bf16x8 af[2][2];
      #pragma unroll
      for (int ii = 0; ii < 2; ++ii) {
        af[ii][0] = *(const bf16x8*)&Ac[(p * 2 + ii) * 1024 + s0];
        af[ii][1] = *(const bf16x8*)&Ac[(p * 2 + ii) * 1024 + s1];
      }
      if (pf) {
        if (p == 0) { stageA2(c ^ 1, k1, 0); stageB1(c ^ 1, k1, 0); }
        else        { stageA2(c ^ 1, k1, 2); stageB1(c ^ 1, k1, 1); }
      }
      __builtin_amdgcn_s_barrier();
      asm volatile("s_waitcnt lgkmcnt(0)" ::: "memory");
      __builtin_amdgcn_sched_barrier(0);
      __builtin_amdgcn_s_setprio(1);
      #pragma unroll
      for (int kk = 0; kk < 2; ++kk)
        #pragma unroll
        for (int ii = 0; ii < 2; ++ii)
          #pragma unroll
          for (int j = 0; j < 4; ++j)
            acc[p * 2 + ii][j] = __builtin_amdgcn_mfma_f32_16x16x32_bf16(
                af[ii][kk], bfr[j][kk], acc[p * 2 + ii][j], 0, 0, 0);
      __builtin_amdgcn_s_setprio(0);
      __builtin_amdgcn_s_barrier();
    }
  }

  #pragma unroll
  for (int j = 0; j < 4; ++j) {
    const int col = n0 + wn + j * 16 + l16;
    const float bvv = bq[col];
    #pragma unroll
    for (int i = 0; i < 4; ++i) {
      #pragma unroll
      for (int r = 0; r < 4; ++r) {
        const int row = m0 + wm + i * 16 + quad * 4 + r;
        float x = acc[i][j][r] + bvv;
        sigq[(long long)row * D_MODEL + col] = (__bf16)(1.f / (1.f + __expf(-x)));
      }
    }
  }
}

// ------------------------------------------------------------- kv fused GEMM
// (unchanged, round-3) computes kT and vT tiles together, fuses exp(k)/ek*v,
// writes ekvT grouped layout directly.
__global__ __launch_bounds__(512) void kv_fused_kernel(
    const __bf16* __restrict__ x1b, const __bf16* __restrict__ x2b,
    const __bf16* __restrict__ wb,
    const float* __restrict__ bk, const float* __restrict__ bv,
    __bf16* __restrict__ ekvT)
{
  extern __shared__ __align__(16) __bf16 smem[];  // W[2][16384] | X[2][8192]

  const int K = D_MODEL;
  const int tid  = threadIdx.x;
  const int wave = tid >> 6;
  const int lane = tid & 63;
  const int quad = lane >> 4;
  const int l16  = lane & 15;
  const int wm   = (wave >> 1) * 64;   // 4 M-waves x 64 d
  const int wn   = (wave & 1) * 64;    // 2 N-waves x 64 rows
  const int F0   = blockIdx.y * 256;   // d tile
  const int L0   = blockIdx.x * 128;   // rows tile
  const int l8r  = lane >> 3;
  const int scol = ((lane & 7) ^ l8r) * 8;
  const bool hi  = (scol >= 32);
  const int sc   = scol & 31;

  const __bf16* Wkb = wb + (long long)D_MODEL * D_MODEL;
  const __bf16* Wvb = wb + 2LL * D_MODEL * D_MODEL;

  const __bf16* gW[4]; const __bf16* gX[2];
  #pragma unroll
  for (int i = 0; i < 4; ++i)
    gW[i] = (hi ? Wvb : Wkb) + (long long)(F0 + i * 64 + wave * 8 + l8r) * K + sc;
  #pragma unroll
  for (int i = 0; i < 2; ++i)
    gX[i] = (hi ? x2b : x1b) + (long long)(L0 + i * 64 + wave * 8 + l8r) * K + sc;

  f32x4 acck[4][4], accv[4][4];
  #pragma unroll
  for (int i = 0; i < 4; ++i)
    #pragma unroll
    for (int j = 0; j < 4; ++j) {
      acck[i][j] = (f32x4){0.f, 0.f, 0.f, 0.f};
      accv[i][j] = (f32x4){0.f, 0.f, 0.f, 0.f};
    }

  auto stageW = [&](int c, int k0) {
    #pragma unroll
    for (int i = 0; i < 4; ++i)
      ASYNC_COPY16(smem + c * 16384 + (i * 64 + wave * 8) * 64, gW[i] + k0);
  };
  auto stageX = [&](int c, int k0) {
    #pragma unroll
    for (int i = 0; i < 2; ++i)
      ASYNC_COPY16(smem + 32768 + c * 8192 + (i * 64 + wave * 8) * 64, gX[i] + k0);
  };

  stageW(0, 0); stageX(0, 0);

  const int s0 = ((quad    ) ^ (l16 & 7)) * 8;    // -> Wk / x1 fragment
  const int s1 = ((quad + 4) ^ (l16 & 7)) * 8;    // -> Wv / x2 fragment

  for (int s = 0; s < 16; ++s) {                  // K step = 32
    const int c = s & 1;
    asm volatile("s_waitcnt vmcnt(0)" ::: "memory");
    __builtin_amdgcn_s_barrier();
    __builtin_amdgcn_sched_barrier(0);

    const __bf16* Wc = smem +         c * 16384 + (wm + l16) * 64;
    const __bf16* Xc = smem + 32768 + c * 8192  + (wn + l16) * 64;
    const bool pf = (s + 1 < 16);
    const int k1 = (s + 1) * 32;

    {
      bf16x8 af[4], bfr[4];
      #pragma unroll
      for (int i = 0; i < 4; ++i) af[i]  = *(const bf16x8*)&Wc[i * 1024 + s0];
      #pragma unroll
      for (int j = 0; j < 4; ++j) bfr[j] = *(const bf16x8*)&Xc[j * 1024 + s0];
      if (pf) stageW(c ^ 1, k1);
      __builtin_amdgcn_s_barrier();
      asm volatile("s_waitcnt lgkmcnt(0)" ::: "memory");
      __builtin_amdgcn_sched_barrier(0);
      __builtin_amdgcn_s_setprio(1);
      #pragma unroll
      for (int i = 0; i < 4; ++i)
        #pragma unroll
        for (int j = 0; j < 4; ++j)
          acck[i][j] = __builtin_amdgcn_mfma_f32_16x16x32_bf16(
              af[i], bfr[j], acck[i][j], 0, 0, 0);
      __builtin_amdgcn_s_setprio(0);
      __builtin_amdgcn_s_barrier();
    }
    {
      bf16x8 af[4], bfr[4];
      #pragma unroll
      for (int i = 0; i < 4; ++i) af[i]  = *(const bf16x8*)&Wc[i * 1024 + s1];
      #pragma unroll
      for (int j = 0; j < 4; ++j) bfr[j] = *(const bf16x8*)&Xc[j * 1024 + s1];
      if (pf) stageX(c ^ 1, k1);
      __builtin_amdgcn_s_barrier();
      asm volatile("s_waitcnt lgkmcnt(0)" ::: "memory");
      __builtin_amdgcn_sched_barrier(0);
      __builtin_amdgcn_s_setprio(1);
      #pragma unroll
      for (int i = 0; i < 4; ++i)
        #pragma unroll
        for (int j = 0; j < 4; ++j)
          accv[i][j] = __builtin_amdgcn_mfma_f32_16x16x32_bf16(
              af[i], bfr[j], accv[i][j], 0, 0, 0);
      __builtin_amdgcn_s_setprio(0);
      __builtin_amdgcn_s_barrier();
    }
  }

  const int b   = L0 >> 11;
  const int sb  = L0 & 2047;
  __bf16* outb = ekvT + (long long)b * (2 * D_MODEL) * SEQ + sb;
  #pragma unroll
  for (int i = 0; i < 4; ++i) {
    #pragma unroll
    for (int r = 0; r < 4; ++r) {
      const int d = F0 + wm + i * 16 + quad * 4 + r;
      const float bkd = bk[d];
      const float bvd = bv[d];
      const int gr = ((d >> 5) << 6) + (d & 31);
      #pragma unroll
      for (int j = 0; j < 4; ++j) {
        const int ss = wn + j * 16 + l16;
        const float kkv = acck[i][j][r] + bkd;
        const float vvv = accv[i][j][r] + bvd;
        const float ekf = __expf(kkv);
        outb[(long long)gr * SEQ + ss]        = (__bf16)(ekf * vvv);
        outb[(long long)(gr + 32) * SEQ + ss] = (__bf16)ekf;
      }
    }
  }
}

// -------------------------------------------- einsum + final, fused epilogue
// REWRITE: 256x256 tile, BK=32, QUAD-buffered LDS (4 x (A16K+B16K) = 128 KiB),
// 8 waves (2Mx4N). Stage tile t+3 during tile t; at tile top a COUNTED
// s_waitcnt vmcnt(8) (tile t's 4 loads are the oldest of 12 in flight,
// issued 3 tiles (~1800cy) earlier > HBM latency -> no stall in steady
// state, and the queue never drains). ONE barrier per tile; the body
// (12 ds_read_b128 + 32 MFMA + 4 global_load_lds) is compiler-scheduled,
// so ds_reads interleave UNDER MFMAs (the old per-phase lgkmcnt(0)
// serialized them -> 37% MfmaUtil).
// Correctness: buf(t+3)&3 == buf(t-1)&3; tile t-1's ds_reads retired before
// its MFMAs issued, which precede tile t's barrier; stage is issued after
// that barrier. Deposits of tile t are visible because EVERY wave executed
// vmcnt(8) (covering its own tile-t loads) before the barrier.
// Swizzle for 32-col rows (64 B): physical row pr = r ^ ((r>>2)&1) (row-
// parity trick) and slot = q ^ (r&3); applied as pre-swizzled global source
// + swizzled read (both sides, rule #21). 8 consecutive lanes -> 8 distinct
// 16B bank positions, 2-way overall (free per m136).
#define ENT32 (SEQ / 32)   // 64 K-tiles

__global__ __launch_bounds__(512) void einsum_fused_kernel(
    const __bf16* __restrict__ A, const __bf16* __restrict__ BtAll,
    const __bf16* __restrict__ sigq, float* __restrict__ out)
{
  extern __shared__ __align__(16) __bf16 smem[];  // A[4][8192] | B[4][8192]

  const int b = blockIdx.z;
  const __bf16* Bt = BtAll + (long long)b * (2 * D_MODEL) * SEQ;

  const int tid  = threadIdx.x;
  const int wave = tid >> 6;
  const int lane = tid & 63;
  const int quad = lane >> 4;
  const int l16  = lane & 15;
  const int wm   = (wave >> 2) * 128;             // 2 wave-rows of 128
  const int wn   = (wave & 3) * 64;               // 4 wave-cols of 64
  const int m0   = blockIdx.x * 256;
  const int n0   = blockIdx.y * 256;

  // ---- staging source (pre-swizzled).  Each 8KB instr covers 128 physical
  // rows x 32 cols; thread tid deposits at inst_base + tid*16B ->
  // physical row tid>>2, slot tid&3.  Source logical row qr = pr^((pr>>2)&1),
  // source col slot = (tid&3) ^ (qr&3).
  const int qr = (tid >> 2) ^ ((tid >> 4) & 1);   // logical row 0..127
  const int cs = (((tid & 3) ^ (qr & 3))) * 8;    // source col (elements)
  const __bf16* gA0 = A  + (long long)(m0 +       qr) * SEQ + cs;
  const __bf16* gA1 = A  + (long long)(m0 + 128 + qr) * SEQ + cs;
  const __bf16* gB0 = Bt + (long long)(n0 +       qr) * SEQ + cs;
  const __bf16* gB1 = Bt + (long long)(n0 + 128 + qr) * SEQ + cs;

  // ---- read-side swizzled offsets (elements)
  const int lxb = l16 ^ ((l16 >> 2) & 1);         // physical row: bit0 ^= bit2
  const int sl  = (quad ^ (l16 & 3)) * 8;         // physical slot for k-slot=quad

  f32x4 acc[8][4];
  #pragma unroll
  for (int i = 0; i < 8; ++i)
    #pragma unroll
    for (int j = 0; j < 4; ++j) acc[i][j] = (f32x4){0.f, 0.f, 0.f, 0.f};

  auto stage = [&](int t) {                       // 4 loads/thread
    const int c  = t & 3;
    const int k0 = t * 32;
    ASYNC_COPY16(smem +         c * 8192 +        tid * 8, gA0 + k0);
    ASYNC_COPY16(smem +         c * 8192 + 4096 + tid * 8, gA1 + k0);
    ASYNC_COPY16(smem + 32768 + c * 8192 +        tid * 8, gB0 + k0);
    ASYNC_COPY16(smem + 32768 + c * 8192 + 4096 + tid * 8, gB1 + k0);
  };

  stage(0); stage(1); stage(2);                   // prologue: 3 tiles deep

  for (int t = 0; t < ENT32; ++t) {
    const int c = t & 3;
    // counted wait: tile t's 4 loads are the oldest; leave up to 8 in flight
    if (t < ENT32 - 2)
      asm volatile("s_waitcnt vmcnt(8) lgkmcnt(0)" ::: "memory");
    else if (t == ENT32 - 2)
      asm volatile("s_waitcnt vmcnt(4) lgkmcnt(0)" ::: "memory");
    else
      asm volatile("s_waitcnt vmcnt(0) lgkmcnt(0)" ::: "memory");
    __builtin_amdgcn_s_barrier();                 // deposits visible block-wide
    __builtin_amdgcn_sched_barrier(0);            // nothing moves across

    const __bf16* Ac = smem +         c * 8192 + (wm + lxb) * 32 + sl;
    const __bf16* Bc = smem + 32768 + c * 8192 + (wn + lxb) * 32 + sl;

    bf16x8 af[8], bfr[4];
    #pragma unroll
    for (int i = 0; i < 8; ++i) af[i]  = *(const bf16x8*)&Ac[i * 512];
    #pragma unroll
    for (int j = 0; j < 4; ++j) bfr[j] = *(const bf16x8*)&Bc[j * 512];

    if (t + 3 < ENT32) stage(t + 3);              // keep 3 tiles in flight

    #pragma unroll
    for (int i = 0; i < 8; ++i)
      #pragma unroll
      for (int j = 0; j < 4; ++j)
        acc[i][j] = __builtin_amdgcn_mfma_f32_16x16x32_bf16(
            af[i], bfr[j], acc[i][j], 0, 0, 0);
  }

  // epilogue: C/D layout col = lane&15, row = quad*4 + reg
  const int g = (n0 + wn) >> 6;                   // channel group 0..15
  #pragma unroll
  for (int j = 0; j < 2; ++j) {
    const int d = g * 32 + j * 16 + l16;
    #pragma unroll
    for (int i = 0; i < 8; ++i) {
      #pragma unroll
      for (int r = 0; r < 4; ++r) {
        const int row = m0 + wm + i * 16 + quad * 4 + r;
        const long long off = ((long long)b * SEQ + row) * D_MODEL + d;
        const float num = acc[i][j][r];
        const float den = acc[i][j + 2][r];
        out[off] = (float)sigq[off] * (num / den);
      }
    }
  }
}

// ---------------------------------------------------------------- launch
extern "C" void kernel_launch(void* const* d_in, const int* in_sizes, int n_in,
                              void* d_out, int out_size, void* d_ws, size_t ws_size,
                              hipStream_t stream) {
  const float* inputs1 = (const float*)d_in[0];
  const float* inputs2 = (const float*)d_in[1];
  const float* Wq = (const float*)d_in[2];
  const float* bq = (const float*)d_in[3];
  const float* Wk = (const float*)d_in[4];
  const float* bk = (const float*)d_in[5];
  const float* Wv = (const float*)d_in[6];
  const float* bv = (const float*)d_in[7];
  const float* posb = (const float*)d_in[8];
  float* out = (float*)d_out;

  // workspace layout
  char* ws = (char*)d_ws;
  const long long szX  = (long long)ROWS * D_MODEL * 2;            // 16.78 MB
  const long long szW  = (long long)D_MODEL * D_MODEL * 2;         // 0.52 MB
  const long long szEB = (long long)SEQ * SEQ * 2;                 // 8.39 MB
  const long long szT  = (long long)BATCH * 2 * D_MODEL * SEQ * 2; // 33.55 MB
  __bf16* x1b   = (__bf16*)(ws);                 ws += szX;
  __bf16* x2b   = (__bf16*)(ws);                 ws += szX;
  __bf16* wb    = (__bf16*)(ws);                 ws += 3 * szW;
  __bf16* expBb = (__bf16*)(ws);                 ws += szEB;
  __bf16* sigq  = (__bf16*)(ws);                 ws += szX;
  __bf16* ekvT  = (__bf16*)(ws);                 ws += szT;

  // one-time: allow big dynamic LDS for the tile kernels
  static bool attr_done = false;
  if (!attr_done) {
    hipFuncSetAttribute((const void*)einsum_fused_kernel,
                        hipFuncAttributeMaxDynamicSharedMemorySize, 131072);
    hipFuncSetAttribute((const void*)q_gemm_kernel,
                        hipFuncAttributeMaxDynamicSharedMemorySize, 98304);
    hipFuncSetAttribute((const void*)kv_fused_kernel,
                        hipFuncAttributeMaxDynamicSharedMemorySize, 98304);
    attr_done = true;
  }

  // 1) all converts, one flat launch
  cvt_all_kernel<<<21248, 256, 0, stream>>>(inputs1, inputs2, posb,
                                            Wq, Wk, Wv,
                                            x1b, x2b, expBb, wb);

  // 2a) q GEMM: 256x128 tiles, grid (64,4) = 256 blocks
  {
    dim3 g(ROWS / 256, D_MODEL / 128);
    q_gemm_kernel<<<g, 512, 98304, stream>>>(x1b, wb, bq, sigq);
  }

  // 2b) kv fused GEMM + exp combine: 256(d)x128(rows), grid (128,2) = 256
  {
    dim3 g(ROWS / 128, D_MODEL / 256);
    kv_fused_kernel<<<g, 512, 98304, stream>>>(x1b, x2b, wb, bk, bv, ekvT);
  }

  // 3) einsum + final fused: 256^2 tile, BK=32 quad-buffered counted-vmcnt
  {
    dim3 g(SEQ / 256, (2 * D_MODEL) / 256, BATCH);
    einsum_fused_kernel<<<g, 512, 131072, stream>>>(expBb, ekvT, sigq, out);
  }
}

// Round 6
// 238.085 us; speedup vs baseline: 1.1581x; 1.0196x over previous
//
#include <hip/hip_runtime.h>

typedef float  f32x4  __attribute__((ext_vector_type(4)));
typedef __bf16 bf16x8 __attribute__((ext_vector_type(8)));
typedef __bf16 bf16x4 __attribute__((ext_vector_type(4)));

#define D_MODEL 512
#define SEQ     2048
#define BATCH   8
#define ROWS    (BATCH * SEQ)   // 16384

// async 16B global -> LDS (each lane deposits at lds_base + lane*16B)
#define ASYNC_COPY16(dst_lds, src_glb)                                          \
  __builtin_amdgcn_global_load_lds(                                             \
      (const __attribute__((address_space(1))) void*)(src_glb),                 \
      (__attribute__((address_space(3))) void*)(dst_lds), 16, 0, 0)

// ------------------------------------------------------------ fused converts
__global__ void cvt_all_kernel(const float* __restrict__ x1,
                               const float* __restrict__ x2,
                               const float* __restrict__ posb,
                               const float* __restrict__ Wq,
                               const float* __restrict__ Wk,
                               const float* __restrict__ Wv,
                               __bf16* __restrict__ x1b, __bf16* __restrict__ x2b,
                               __bf16* __restrict__ expBb, __bf16* __restrict__ wb)
{
  const int blk = blockIdx.x;
  if (blk < 16384) {
    const float* in = (blk < 8192) ? x1 : x2;
    __bf16* out = (blk < 8192) ? x1b : x2b;
    const int i = (blk & 8191) * 256 + threadIdx.x;
    float4 v = ((const float4*)in)[i];
    bf16x4 o = { (__bf16)v.x, (__bf16)v.y, (__bf16)v.z, (__bf16)v.w };
    ((bf16x4*)out)[i] = o;
  } else if (blk < 20480) {
    const int i = (blk - 16384) * 256 + threadIdx.x;
    float4 v = ((const float4*)posb)[i];
    bf16x4 o = { (__bf16)__expf(v.x), (__bf16)__expf(v.y),
                 (__bf16)__expf(v.z), (__bf16)__expf(v.w) };
    ((bf16x4*)expBb)[i] = o;
  } else {
    const int i = (blk - 20480) * 256 + threadIdx.x;
    const int nW4 = D_MODEL * D_MODEL / 4;
    const float* src = (i < nW4) ? Wq : (i < 2 * nW4) ? Wk : Wv;
    const int ii = i - ((i < nW4) ? 0 : (i < 2 * nW4) ? nW4 : 2 * nW4);
    float4 v = ((const float4*)src)[ii];
    bf16x4 o = { (__bf16)v.x, (__bf16)v.y, (__bf16)v.z, (__bf16)v.w };
    ((bf16x4*)wb)[i] = o;
  }
}

// ------------------------------------------------------------- q GEMM
// q = sigmoid(x1*Wq^T + bq) -> sigq [rows][d], bf16.   (unchanged, round-3)
__global__ __launch_bounds__(512) void q_gemm_kernel(
    const __bf16* __restrict__ x1b, const __bf16* __restrict__ wb,
    const float* __restrict__ bq, __bf16* __restrict__ sigq)
{
  extern __shared__ __align__(16) __bf16 smem[];  // A[2][16384] | B[2][8192]

  const int K = D_MODEL;
  const int tid  = threadIdx.x;
  const int wave = tid >> 6;
  const int lane = tid & 63;
  const int quad = lane >> 4;
  const int l16  = lane & 15;
  const int wm   = (wave >> 1) * 64;   // 4 M-waves x 64 rows
  const int wn   = (wave & 1) * 64;    // 2 N-waves x 64 d
  const int m0   = blockIdx.x * 256;   // rows tile
  const int n0   = blockIdx.y * 128;   // d tile
  const int l8r  = lane >> 3;
  const int scol = ((lane & 7) ^ l8r) * 8;        // pre-swizzled global col

  const __bf16* ga[4]; const __bf16* gb[2];
  #pragma unroll
  for (int i = 0; i < 4; ++i)
    ga[i] = x1b + (long long)(m0 + i * 64 + wave * 8 + l8r) * K + scol;
  #pragma unroll
  for (int i = 0; i < 2; ++i)
    gb[i] = wb + (long long)(n0 + i * 64 + wave * 8 + l8r) * K + scol;

  f32x4 acc[4][4];
  #pragma unroll
  for (int i = 0; i < 4; ++i)
    #pragma unroll
    for (int j = 0; j < 4; ++j) acc[i][j] = (f32x4){0.f, 0.f, 0.f, 0.f};

  auto stageA2 = [&](int c, int k0, int i0) {
    ASYNC_COPY16(smem + c * 16384 + (i0 * 64 + wave * 8) * 64, ga[i0] + k0);
    ASYNC_COPY16(smem + c * 16384 + ((i0 + 1) * 64 + wave * 8) * 64, ga[i0 + 1] + k0);
  };
  auto stageB1 = [&](int c, int k0, int i) {
    ASYNC_COPY16(smem + 32768 + c * 8192 + (i * 64 + wave * 8) * 64, gb[i] + k0);
  };

  stageA2(0, 0, 0); stageA2(0, 0, 2);
  stageB1(0, 0, 0); stageB1(0, 0, 1);             // prologue (6 loads)

  const int s0 = ((quad    ) ^ (l16 & 7)) * 8;
  const int s1 = ((quad + 4) ^ (l16 & 7)) * 8;

  for (int t = 0; t < 8; ++t) {
    const int c = t & 1;
    asm volatile("s_waitcnt vmcnt(0)" ::: "memory");
    __builtin_amdgcn_s_barrier();
    __builtin_amdgcn_sched_barrier(0);

    const __bf16* Ac = smem +         c * 16384 + (wm + l16) * 64;
    const __bf16* Bc = smem + 32768 + c * 8192  + (wn + l16) * 64;
    const bool pf = (t + 1 < 8);
    const int k1 = (t + 1) * 64;

    bf16x8 bfr[4][2];
    #pragma unroll
    for (int p = 0; p < 2; ++p) {
      if (p == 0) {
        #pragma unroll
        for (int j = 0; j < 4; ++j) {
          bfr[j][0] = *(const bf16x8*)&Bc[j * 1024 + s0];
          bfr[j][1] = *(const bf16x8*)&Bc[j * 1024 + s1];
        }
      }
      bf16x8 af[2][2];
      #pragma unroll
      for (int ii = 0; ii < 2; ++ii) {
        af[ii][0] = *(const bf16x8*)&Ac[(p * 2 + ii) * 1024 + s0];
        af[ii][1] = *(const bf16x8*)&Ac[(p * 2 + ii) * 1024 + s1];
      }
      if (pf) {
        if (p == 0) { stageA2(c ^ 1, k1, 0); stageB1(c ^ 1, k1, 0); }
        else        { stageA2(c ^ 1, k1, 2); stageB1(c ^ 1, k1, 1); }
      }
      __builtin_amdgcn_s_barrier();
      asm volatile("s_waitcnt lgkmcnt(0)" ::: "memory");
      __builtin_amdgcn_sched_barrier(0);
      __builtin_amdgcn_s_setprio(1);
      #pragma unroll
      for (int kk = 0; kk < 2; ++kk)
        #pragma unroll
        for (int ii = 0; ii < 2; ++ii)
          #pragma unroll
          for (int j = 0; j < 4; ++j)
            acc[p * 2 + ii][j] = __builtin_amdgcn_mfma_f32_16x16x32_bf16(
                af[ii][kk], bfr[j][kk], acc[p * 2 + ii][j], 0, 0, 0);
      __builtin_amdgcn_s_setprio(0);
      __builtin_amdgcn_s_barrier();
    }
  }

  #pragma unroll
  for (int j = 0; j < 4; ++j) {
    const int col = n0 + wn + j * 16 + l16;
    const float bvv = bq[col];
    #pragma unroll
    for (int i = 0; i < 4; ++i) {
      #pragma unroll
      for (int r = 0; r < 4; ++r) {
        const int row = m0 + wm + i * 16 + quad * 4 + r;
        float x = acc[i][j][r] + bvv;
        sigq[(long long)row * D_MODEL + col] = (__bf16)(1.f / (1.f + __expf(-x)));
      }
    }
  }
}

// ------------------------------------------------------------- kv fused GEMM
// (unchanged, round-3) computes kT and vT tiles together, fuses exp(k)/ek*v,
// writes ekvT grouped layout directly.
__global__ __launch_bounds__(512) void kv_fused_kernel(
    const __bf16* __restrict__ x1b, const __bf16* __restrict__ x2b,
    const __bf16* __restrict__ wb,
    const float* __restrict__ bk, const float* __restrict__ bv,
    __bf16* __restrict__ ekvT)
{
  extern __shared__ __align__(16) __bf16 smem[];  // W[2][16384] | X[2][8192]

  const int K = D_MODEL;
  const int tid  = threadIdx.x;
  const int wave = tid >> 6;
  const int lane = tid & 63;
  const int quad = lane >> 4;
  const int l16  = lane & 15;
  const int wm   = (wave >> 1) * 64;   // 4 M-waves x 64 d
  const int wn   = (wave & 1) * 64;    // 2 N-waves x 64 rows
  const int F0   = blockIdx.y * 256;   // d tile
  const int L0   = blockIdx.x * 128;   // rows tile
  const int l8r  = lane >> 3;
  const int scol = ((lane & 7) ^ l8r) * 8;
  const bool hi  = (scol >= 32);
  const int sc   = scol & 31;

  const __bf16* Wkb = wb + (long long)D_MODEL * D_MODEL;
  const __bf16* Wvb = wb + 2LL * D_MODEL * D_MODEL;

  const __bf16* gW[4]; const __bf16* gX[2];
  #pragma unroll
  for (int i = 0; i < 4; ++i)
    gW[i] = (hi ? Wvb : Wkb) + (long long)(F0 + i * 64 + wave * 8 + l8r) * K + sc;
  #pragma unroll
  for (int i = 0; i < 2; ++i)
    gX[i] = (hi ? x2b : x1b) + (long long)(L0 + i * 64 + wave * 8 + l8r) * K + sc;

  f32x4 acck[4][4], accv[4][4];
  #pragma unroll
  for (int i = 0; i < 4; ++i)
    #pragma unroll
    for (int j = 0; j < 4; ++j) {
      acck[i][j] = (f32x4){0.f, 0.f, 0.f, 0.f};
      accv[i][j] = (f32x4){0.f, 0.f, 0.f, 0.f};
    }

  auto stageW = [&](int c, int k0) {
    #pragma unroll
    for (int i = 0; i < 4; ++i)
      ASYNC_COPY16(smem + c * 16384 + (i * 64 + wave * 8) * 64, gW[i] + k0);
  };
  auto stageX = [&](int c, int k0) {
    #pragma unroll
    for (int i = 0; i < 2; ++i)
      ASYNC_COPY16(smem + 32768 + c * 8192 + (i * 64 + wave * 8) * 64, gX[i] + k0);
  };

  stageW(0, 0); stageX(0, 0);

  const int s0 = ((quad    ) ^ (l16 & 7)) * 8;    // -> Wk / x1 fragment
  const int s1 = ((quad + 4) ^ (l16 & 7)) * 8;    // -> Wv / x2 fragment

  for (int s = 0; s < 16; ++s) {                  // K step = 32
    const int c = s & 1;
    asm volatile("s_waitcnt vmcnt(0)" ::: "memory");
    __builtin_amdgcn_s_barrier();
    __builtin_amdgcn_sched_barrier(0);

    const __bf16* Wc = smem +         c * 16384 + (wm + l16) * 64;
    const __bf16* Xc = smem + 32768 + c * 8192  + (wn + l16) * 64;
    const bool pf = (s + 1 < 16);
    const int k1 = (s + 1) * 32;

    {
      bf16x8 af[4], bfr[4];
      #pragma unroll
      for (int i = 0; i < 4; ++i) af[i]  = *(const bf16x8*)&Wc[i * 1024 + s0];
      #pragma unroll
      for (int j = 0; j < 4; ++j) bfr[j] = *(const bf16x8*)&Xc[j * 1024 + s0];
      if (pf) stageW(c ^ 1, k1);
      __builtin_amdgcn_s_barrier();
      asm volatile("s_waitcnt lgkmcnt(0)" ::: "memory");
      __builtin_amdgcn_sched_barrier(0);
      __builtin_amdgcn_s_setprio(1);
      #pragma unroll
      for (int i = 0; i < 4; ++i)
        #pragma unroll
        for (int j = 0; j < 4; ++j)
          acck[i][j] = __builtin_amdgcn_mfma_f32_16x16x32_bf16(
              af[i], bfr[j], acck[i][j], 0, 0, 0);
      __builtin_amdgcn_s_setprio(0);
      __builtin_amdgcn_s_barrier();
    }
    {
      bf16x8 af[4], bfr[4];
      #pragma unroll
      for (int i = 0; i < 4; ++i) af[i]  = *(const bf16x8*)&Wc[i * 1024 + s1];
      #pragma unroll
      for (int j = 0; j < 4; ++j) bfr[j] = *(const bf16x8*)&Xc[j * 1024 + s1];
      if (pf) stageX(c ^ 1, k1);
      __builtin_amdgcn_s_barrier();
      asm volatile("s_waitcnt lgkmcnt(0)" ::: "memory");
      __builtin_amdgcn_sched_barrier(0);
      __builtin_amdgcn_s_setprio(1);
      #pragma unroll
      for (int i = 0; i < 4; ++i)
        #pragma unroll
        for (int j = 0; j < 4; ++j)
          accv[i][j] = __builtin_amdgcn_mfma_f32_16x16x32_bf16(
              af[i], bfr[j], accv[i][j], 0, 0, 0);
      __builtin_amdgcn_s_setprio(0);
      __builtin_amdgcn_s_barrier();
    }
  }

  const int b   = L0 >> 11;
  const int sb  = L0 & 2047;
  __bf16* outb = ekvT + (long long)b * (2 * D_MODEL) * SEQ + sb;
  #pragma unroll
  for (int i = 0; i < 4; ++i) {
    #pragma unroll
    for (int r = 0; r < 4; ++r) {
      const int d = F0 + wm + i * 16 + quad * 4 + r;
      const float bkd = bk[d];
      const float bvd = bv[d];
      const int gr = ((d >> 5) << 6) + (d & 31);
      #pragma unroll
      for (int j = 0; j < 4; ++j) {
        const int ss = wn + j * 16 + l16;
        const float kkv = acck[i][j][r] + bkd;
        const float vvv = accv[i][j][r] + bvd;
        const float ekf = __expf(kkv);
        outb[(long long)gr * SEQ + ss]        = (__bf16)(ekf * vvv);
        outb[(long long)(gr + 32) * SEQ + ss] = (__bf16)ekf;
      }
    }
  }
}

// -------------------------------------------- einsum + final, fused epilogue
// 256x256 tile, BK=32, QUAD-buffered (4 x 16KiB x {A,B} = 128 KiB), 8 waves
// (2Mx4N), single barrier/tile, counted vmcnt(8) (queue never drains).
// ROUND-6 FIX: LDS repacked into the PROVEN 128B-row geometry. Each
// 128-logical-row x 32-col half-tile is stored as 64 phys rows x 8 granules
// of 16B; granule g of phys row P holds logical (row = 2P + (u>>2),
// kslot = u&3) with u = g ^ (P&7). bank = 4*granule only (128B rows), and
// any aligned 8-lane group reads 8 distinct granules -> zero conflicts
// (same structure as the zero-conflict 64-col layout). Round-5's 64B-row
// parity swizzle measured 16 conflict-cycles/ds_read (6.29M/dispatch).
// Both-sides (rule #21): pre-swizzled global source + swizzled read.
// XCD remap: 256 blocks; orig = (lid&7)*32 + lid>>3 gives each XCD one
// whole batch -> its 4MB ekvT slice is L2-resident.
#define ENT32 (SEQ / 32)   // 64 K-tiles

__global__ __launch_bounds__(512) void einsum_fused_kernel(
    const __bf16* __restrict__ A, const __bf16* __restrict__ BtAll,
    const __bf16* __restrict__ sigq, float* __restrict__ out)
{
  extern __shared__ __align__(16) __bf16 smem[];  // A[4][8192] | B[4][8192]

  const int tid  = threadIdx.x;
  const int wave = tid >> 6;
  const int lane = tid & 63;
  const int quad = lane >> 4;
  const int l16  = lane & 15;
  const int wm   = (wave >> 2) * 128;             // 2 wave-rows of 128
  const int wn   = (wave & 3) * 64;               // 4 wave-cols of 64

  // XCD-aware remap: lid -> orig; XCD k (lid%8==k) owns batch k entirely.
  const int lid  = blockIdx.x + (blockIdx.y << 3) + (blockIdx.z << 5);
  const int orig = ((lid & 7) << 5) + (lid >> 3);
  const int m0   = (orig & 7) * 256;              // seq tile
  const int n0   = ((orig >> 3) & 3) * 256;       // channel-group tile
  const int b    = orig >> 5;                     // batch

  const __bf16* Bt = BtAll + (long long)b * (2 * D_MODEL) * SEQ;

  // ---- staging source (pre-swizzled for the 128B-row granule layout).
  // thread tid deposits 16B at phys (P = tid>>3, g = tid&7) of one half-tile;
  // source logical row lr = 2P + (u>>2), col slot u&3, u = g ^ (P&7).
  const int pr = tid >> 3;
  const int u  = (tid & 7) ^ (pr & 7);
  const int lr = 2 * pr + (u >> 2);               // logical row 0..127
  const int cs = (u & 3) * 8;                     // source col (elements)
  const __bf16* gA0 = A  + (long long)(m0 +       lr) * SEQ + cs;
  const __bf16* gA1 = A  + (long long)(m0 + 128 + lr) * SEQ + cs;
  const __bf16* gB0 = Bt + (long long)(n0 +       lr) * SEQ + cs;
  const __bf16* gB1 = Bt + (long long)(n0 + 128 + lr) * SEQ + cs;

  // ---- read-side swizzled offsets (elements within a buffer)
  // lane wants (logical row = 16i + l16 within its half, kslot = quad):
  // phys row = 8i + (l16>>1), granule = ((l16&1)<<2 | quad) ^ (l16>>1).
  const int rl   = l16 >> 1;
  const int gran = (((l16 & 1) << 2) | quad) ^ rl;
  const int offA = (wave >> 2) * 4096 + rl * 64 + gran * 8;
  const int offB = (wn >> 7) * 4096 + ((wn & 127) >> 1) * 64 + rl * 64 + gran * 8;

  f32x4 acc[8][4];
  #pragma unroll
  for (int i = 0; i < 8; ++i)
    #pragma unroll
    for (int j = 0; j < 4; ++j) acc[i][j] = (f32x4){0.f, 0.f, 0.f, 0.f};

  auto stage = [&](int t) {                       // 4 loads/thread
    const int c  = t & 3;
    const int k0 = t * 32;
    ASYNC_COPY16(smem +         c * 8192 +        tid * 8, gA0 + k0);
    ASYNC_COPY16(smem +         c * 8192 + 4096 + tid * 8, gA1 + k0);
    ASYNC_COPY16(smem + 32768 + c * 8192 +        tid * 8, gB0 + k0);
    ASYNC_COPY16(smem + 32768 + c * 8192 + 4096 + tid * 8, gB1 + k0);
  };

  stage(0); stage(1); stage(2);                   // prologue: 3 tiles deep

  for (int t = 0; t < ENT32; ++t) {
    const int c = t & 3;
    // counted wait: tile t's 4 loads are the oldest; keep 8 in flight
    if (t < ENT32 - 2)
      asm volatile("s_waitcnt vmcnt(8) lgkmcnt(0)" ::: "memory");
    else if (t == ENT32 - 2)
      asm volatile("s_waitcnt vmcnt(4) lgkmcnt(0)" ::: "memory");
    else
      asm volatile("s_waitcnt vmcnt(0) lgkmcnt(0)" ::: "memory");
    __builtin_amdgcn_s_barrier();                 // deposits visible block-wide
    __builtin_amdgcn_sched_barrier(0);            // nothing moves across

    const __bf16* Ac = smem +         c * 8192 + offA;
    const __bf16* Bc = smem + 32768 + c * 8192 + offB;

    bf16x8 af[8], bfr[4];
    #pragma unroll
    for (int i = 0; i < 8; ++i) af[i]  = *(const bf16x8*)&Ac[i * 512];
    #pragma unroll
    for (int j = 0; j < 4; ++j) bfr[j] = *(const bf16x8*)&Bc[j * 512];

    if (t + 3 < ENT32) stage(t + 3);              // keep 3 tiles in flight

    #pragma unroll
    for (int i = 0; i < 8; ++i)
      #pragma unroll
      for (int j = 0; j < 4; ++j)
        acc[i][j] = __builtin_amdgcn_mfma_f32_16x16x32_bf16(
            af[i], bfr[j], acc[i][j], 0, 0, 0);
  }

  // epilogue: C/D layout col = lane&15, row = quad*4 + reg
  const int g = (n0 + wn) >> 6;                   // channel group 0..15
  #pragma unroll
  for (int j = 0; j < 2; ++j) {
    const int d = g * 32 + j * 16 + l16;
    #pragma unroll
    for (int i = 0; i < 8; ++i) {
      #pragma unroll
      for (int r = 0; r < 4; ++r) {
        const int row = m0 + wm + i * 16 + quad * 4 + r;
        const long long off = ((long long)b * SEQ + row) * D_MODEL + d;
        const float num = acc[i][j][r];
        const float den = acc[i][j + 2][r];
        out[off] = (float)sigq[off] * (num / den);
      }
    }
  }
}

// ---------------------------------------------------------------- launch
extern "C" void kernel_launch(void* const* d_in, const int* in_sizes, int n_in,
                              void* d_out, int out_size, void* d_ws, size_t ws_size,
                              hipStream_t stream) {
  const float* inputs1 = (const float*)d_in[0];
  const float* inputs2 = (const float*)d_in[1];
  const float* Wq = (const float*)d_in[2];
  const float* bq = (const float*)d_in[3];
  const float* Wk = (const float*)d_in[4];
  const float* bk = (const float*)d_in[5];
  const float* Wv = (const float*)d_in[6];
  const float* bv = (const float*)d_in[7];
  const float* posb = (const float*)d_in[8];
  float* out = (float*)d_out;

  // workspace layout
  char* ws = (char*)d_ws;
  const long long szX  = (long long)ROWS * D_MODEL * 2;            // 16.78 MB
  const long long szW  = (long long)D_MODEL * D_MODEL * 2;         // 0.52 MB
  const long long szEB = (long long)SEQ * SEQ * 2;                 // 8.39 MB
  const long long szT  = (long long)BATCH * 2 * D_MODEL * SEQ * 2; // 33.55 MB
  __bf16* x1b   = (__bf16*)(ws);                 ws += szX;
  __bf16* x2b   = (__bf16*)(ws);                 ws += szX;
  __bf16* wb    = (__bf16*)(ws);                 ws += 3 * szW;
  __bf16* expBb = (__bf16*)(ws);                 ws += szEB;
  __bf16* sigq  = (__bf16*)(ws);                 ws += szX;
  __bf16* ekvT  = (__bf16*)(ws);                 ws += szT;

  // one-time: allow big dynamic LDS for the tile kernels
  static bool attr_done = false;
  if (!attr_done) {
    hipFuncSetAttribute((const void*)einsum_fused_kernel,
                        hipFuncAttributeMaxDynamicSharedMemorySize, 131072);
    hipFuncSetAttribute((const void*)q_gemm_kernel,
                        hipFuncAttributeMaxDynamicSharedMemorySize, 98304);
    hipFuncSetAttribute((const void*)kv_fused_kernel,
                        hipFuncAttributeMaxDynamicSharedMemorySize, 98304);
    attr_done = true;
  }

  // 1) all converts, one flat launch
  cvt_all_kernel<<<21248, 256, 0, stream>>>(inputs1, inputs2, posb,
                                            Wq, Wk, Wv,
                                            x1b, x2b, expBb, wb);

  // 2a) q GEMM: 256x128 tiles, grid (64,4) = 256 blocks
  {
    dim3 g(ROWS / 256, D_MODEL / 128);
    q_gemm_kernel<<<g, 512, 98304, stream>>>(x1b, wb, bq, sigq);
  }

  // 2b) kv fused GEMM + exp combine: 256(d)x128(rows), grid (128,2) = 256
  {
    dim3 g(ROWS / 128, D_MODEL / 256);
    kv_fused_kernel<<<g, 512, 98304, stream>>>(x1b, x2b, wb, bk, bv, ekvT);
  }

  // 3) einsum + final fused: 256^2 tile, BK=32 quad-buffered counted-vmcnt,
  //    conflict-free 128B-row granule layout + XCD remap
  {
    dim3 g(SEQ / 256, (2 * D_MODEL) / 256, BATCH);
    einsum_fused_kernel<<<g, 512, 131072, stream>>>(expBb, ekvT, sigq, out);
  }
}